// Round 1
// baseline (6648.051 us; speedup 1.0000x reference)
//
#include <hip/hip_runtime.h>

typedef float fx4 __attribute__((ext_vector_type(4)));

static __device__ __forceinline__ fx4 ld4(const float* p) {
    return *reinterpret_cast<const fx4*>(p);
}
static __device__ __forceinline__ void st4(float* p, fx4 v) {
    *reinterpret_cast<fx4*>(p) = v;
}
static __device__ __forceinline__ fx4 relu4(fx4 v) {
    fx4 r;
    #pragma unroll
    for (int j = 0; j < 4; ++j) r[j] = fmaxf(v[j], 0.0f);
    return r;
}

// out = relu(X@W1 + b1) @ W2 + b2
// X: [M, K1], W1: [K1,128], W2: [128,128], Out: [M,128]
// Block: 256 threads, 64 rows per block.
template <int K1>
__global__ __launch_bounds__(256) void fused_mlp_kernel(
    const float* __restrict__ X, const float* __restrict__ W1,
    const float* __restrict__ b1, const float* __restrict__ W2,
    const float* __restrict__ b2, float* __restrict__ Out, int M)
{
    __shared__ float Xs[64][K1 + 4];
    __shared__ float Hs[64][132];
    const int tid = threadIdx.x;
    const int row0 = blockIdx.x * 64;
    constexpr int RP = K1 / 4;   // float4s per input row

    // stage X tile
    for (int i = tid; i < 64 * RP; i += 256) {
        int r = i / RP, c = (i % RP) * 4;
        fx4 v = {0.f, 0.f, 0.f, 0.f};
        int gr = row0 + r;
        if (gr < M) v = ld4(X + (size_t)gr * K1 + c);
        st4(&Xs[r][c], v);
    }
    __syncthreads();

    const int ty = tid >> 4;   // 0..15 -> rows ty*4..+4
    const int tx = tid & 15;   // cols tx*8..+8

    // phase 1: H = relu(Xs @ W1 + b1)
    fx4 acc[4][2];
    #pragma unroll
    for (int r = 0; r < 4; ++r) { acc[r][0] = 0.f; acc[r][1] = 0.f; }
    for (int k = 0; k < K1; k += 4) {
        fx4 xr[4];
        #pragma unroll
        for (int r = 0; r < 4; ++r) xr[r] = ld4(&Xs[ty * 4 + r][k]);
        #pragma unroll
        for (int kk = 0; kk < 4; ++kk) {
            fx4 wa = ld4(W1 + (size_t)(k + kk) * 128 + tx * 8);
            fx4 wb = ld4(W1 + (size_t)(k + kk) * 128 + tx * 8 + 4);
            #pragma unroll
            for (int r = 0; r < 4; ++r) {
                acc[r][0] += xr[r][kk] * wa;
                acc[r][1] += xr[r][kk] * wb;
            }
        }
    }
    {
        fx4 ba = ld4(b1 + tx * 8), bb = ld4(b1 + tx * 8 + 4);
        #pragma unroll
        for (int r = 0; r < 4; ++r) {
            st4(&Hs[ty * 4 + r][tx * 8], relu4(acc[r][0] + ba));
            st4(&Hs[ty * 4 + r][tx * 8 + 4], relu4(acc[r][1] + bb));
        }
    }
    __syncthreads();

    // phase 2: Out = Hs @ W2 + b2
    fx4 acc2[4][2];
    #pragma unroll
    for (int r = 0; r < 4; ++r) { acc2[r][0] = 0.f; acc2[r][1] = 0.f; }
    for (int k = 0; k < 128; k += 4) {
        fx4 xr[4];
        #pragma unroll
        for (int r = 0; r < 4; ++r) xr[r] = ld4(&Hs[ty * 4 + r][k]);
        #pragma unroll
        for (int kk = 0; kk < 4; ++kk) {
            fx4 wa = ld4(W2 + (size_t)(k + kk) * 128 + tx * 8);
            fx4 wb = ld4(W2 + (size_t)(k + kk) * 128 + tx * 8 + 4);
            #pragma unroll
            for (int r = 0; r < 4; ++r) {
                acc2[r][0] += xr[r][kk] * wa;
                acc2[r][1] += xr[r][kk] * wb;
            }
        }
    }
    {
        fx4 ba = ld4(b2 + tx * 8), bb = ld4(b2 + tx * 8 + 4);
        #pragma unroll
        for (int r = 0; r < 4; ++r) {
            int gr = row0 + ty * 4 + r;
            if (gr < M) {
                st4(Out + (size_t)gr * 128 + tx * 8, acc2[r][0] + ba);
                st4(Out + (size_t)gr * 128 + tx * 8 + 4, acc2[r][1] + bb);
            }
        }
    }
}

// Out = X @ W (+ bias), X: [M,128], W: [128,128]
__global__ __launch_bounds__(256) void gemm128_kernel(
    const float* __restrict__ X, const float* __restrict__ W,
    const float* __restrict__ bias, float* __restrict__ Out, int M)
{
    __shared__ float Xs[64][132];
    const int tid = threadIdx.x;
    const int row0 = blockIdx.x * 64;

    for (int i = tid; i < 64 * 32; i += 256) {
        int r = i >> 5, c = (i & 31) * 4;
        fx4 v = {0.f, 0.f, 0.f, 0.f};
        int gr = row0 + r;
        if (gr < M) v = ld4(X + (size_t)gr * 128 + c);
        st4(&Xs[r][c], v);
    }
    __syncthreads();

    const int ty = tid >> 4;
    const int tx = tid & 15;

    fx4 acc[4][2];
    #pragma unroll
    for (int r = 0; r < 4; ++r) { acc[r][0] = 0.f; acc[r][1] = 0.f; }
    for (int k = 0; k < 128; k += 4) {
        fx4 xr[4];
        #pragma unroll
        for (int r = 0; r < 4; ++r) xr[r] = ld4(&Xs[ty * 4 + r][k]);
        #pragma unroll
        for (int kk = 0; kk < 4; ++kk) {
            fx4 wa = ld4(W + (size_t)(k + kk) * 128 + tx * 8);
            fx4 wb = ld4(W + (size_t)(k + kk) * 128 + tx * 8 + 4);
            #pragma unroll
            for (int r = 0; r < 4; ++r) {
                acc[r][0] += xr[r][kk] * wa;
                acc[r][1] += xr[r][kk] * wb;
            }
        }
    }
    fx4 ba = {0.f,0.f,0.f,0.f}, bb = {0.f,0.f,0.f,0.f};
    if (bias) { ba = ld4(bias + tx * 8); bb = ld4(bias + tx * 8 + 4); }
    #pragma unroll
    for (int r = 0; r < 4; ++r) {
        int gr = row0 + ty * 4 + r;
        if (gr < M) {
            st4(Out + (size_t)gr * 128 + tx * 8, acc[r][0] + ba);
            st4(Out + (size_t)gr * 128 + tx * 8 + 4, acc[r][1] + bb);
        }
    }
}

// Per block: 32 edges.
//  Ep = edge_emb[e]@W1b + b1  (computed in-place in Es)
//  Hf = relu(P1[src] + Ep + P3[dst]);  Hb = relu(P1[dst] + Ep + P3[src])
//  Mf = Hf@W2 + b2 -> atomicAdd newEmb[dst];  Mb -> newEmb[src]
__global__ __launch_bounds__(256) void message_kernel(
    const float* __restrict__ edge_emb, const float* __restrict__ P1,
    const float* __restrict__ P3, const int* __restrict__ edge_list,
    const float* __restrict__ W1b, const float* __restrict__ b1,
    const float* __restrict__ W2, const float* __restrict__ b2,
    float* __restrict__ newEmb, int NE)
{
    __shared__ float Es[32][132];
    __shared__ float Hs[64][132];
    __shared__ int esrc[32], edst[32];
    const int tid = threadIdx.x;
    const int e0 = blockIdx.x * 32;

    if (tid < 32) {
        int e = e0 + tid;
        esrc[tid] = (e < NE) ? edge_list[2 * (size_t)e] : 0;
        edst[tid] = (e < NE) ? edge_list[2 * (size_t)e + 1] : 0;
    }
    for (int i = tid; i < 32 * 32; i += 256) {
        int r = i >> 5, c = (i & 31) * 4;
        fx4 v = {0.f, 0.f, 0.f, 0.f};
        int e = e0 + r;
        if (e < NE) v = ld4(edge_emb + (size_t)e * 128 + c);
        st4(&Es[r][c], v);
    }
    __syncthreads();

    const int ty = tid >> 4;   // 0..15
    const int tx = tid & 15;

    // phase A: Ep = Es @ W1b + b1 (rows ty*2..+2)
    fx4 accA[2][2];
    #pragma unroll
    for (int r = 0; r < 2; ++r) { accA[r][0] = 0.f; accA[r][1] = 0.f; }
    for (int k = 0; k < 128; k += 4) {
        fx4 xr[2];
        #pragma unroll
        for (int r = 0; r < 2; ++r) xr[r] = ld4(&Es[ty * 2 + r][k]);
        #pragma unroll
        for (int kk = 0; kk < 4; ++kk) {
            fx4 wa = ld4(W1b + (size_t)(k + kk) * 128 + tx * 8);
            fx4 wb = ld4(W1b + (size_t)(k + kk) * 128 + tx * 8 + 4);
            #pragma unroll
            for (int r = 0; r < 2; ++r) {
                accA[r][0] += xr[r][kk] * wa;
                accA[r][1] += xr[r][kk] * wb;
            }
        }
    }
    __syncthreads();
    {
        fx4 ba = ld4(b1 + tx * 8), bb = ld4(b1 + tx * 8 + 4);
        #pragma unroll
        for (int r = 0; r < 2; ++r) {
            st4(&Es[ty * 2 + r][tx * 8], accA[r][0] + ba);
            st4(&Es[ty * 2 + r][tx * 8 + 4], accA[r][1] + bb);
        }
    }
    __syncthreads();

    // phase B: build Hf (rows 0..31) / Hb (rows 32..63)
    for (int i = tid; i < 32 * 32; i += 256) {
        int r = i >> 5, c = (i & 31) * 4;
        int s = esrc[r], d = edst[r];
        fx4 ep = ld4(&Es[r][c]);
        fx4 p1s = ld4(P1 + (size_t)s * 128 + c);
        fx4 p1d = ld4(P1 + (size_t)d * 128 + c);
        fx4 p3s = ld4(P3 + (size_t)s * 128 + c);
        fx4 p3d = ld4(P3 + (size_t)d * 128 + c);
        st4(&Hs[r][c], relu4(p1s + ep + p3d));
        st4(&Hs[32 + r][c], relu4(p1d + ep + p3s));
    }
    __syncthreads();

    // phase C: M = Hs @ W2 + b2, scatter
    fx4 accC[4][2];
    #pragma unroll
    for (int r = 0; r < 4; ++r) { accC[r][0] = 0.f; accC[r][1] = 0.f; }
    for (int k = 0; k < 128; k += 4) {
        fx4 xr[4];
        #pragma unroll
        for (int r = 0; r < 4; ++r) xr[r] = ld4(&Hs[ty * 4 + r][k]);
        #pragma unroll
        for (int kk = 0; kk < 4; ++kk) {
            fx4 wa = ld4(W2 + (size_t)(k + kk) * 128 + tx * 8);
            fx4 wb = ld4(W2 + (size_t)(k + kk) * 128 + tx * 8 + 4);
            #pragma unroll
            for (int r = 0; r < 4; ++r) {
                accC[r][0] += xr[r][kk] * wa;
                accC[r][1] += xr[r][kk] * wb;
            }
        }
    }
    fx4 ba = ld4(b2 + tx * 8), bb = ld4(b2 + tx * 8 + 4);
    #pragma unroll
    for (int r = 0; r < 4; ++r) {
        int row = ty * 4 + r;        // 0..63
        int er = row & 31;
        int e = e0 + er;
        if (e >= NE) continue;
        int tgt = (row < 32) ? edst[er] : esrc[er];
        fx4 m0 = accC[r][0] + ba, m1 = accC[r][1] + bb;
        float* p = newEmb + (size_t)tgt * 128 + tx * 8;
        #pragma unroll
        for (int j = 0; j < 4; ++j) atomicAdd(p + j, m0[j]);
        #pragma unroll
        for (int j = 0; j < 4; ++j) atomicAdd(p + 4 + j, m1[j]);
    }
}

extern "C" void kernel_launch(void* const* d_in, const int* in_sizes, int n_in,
                              void* d_out, int out_size, void* d_ws, size_t ws_size,
                              hipStream_t stream) {
    const float* node_f    = (const float*)d_in[0];
    const int*   edge_list = (const int*)d_in[1];
    const float* edge_f    = (const float*)d_in[2];
    const float* ne_w1 = (const float*)d_in[4];
    const float* ne_b1 = (const float*)d_in[5];
    const float* ne_w2 = (const float*)d_in[6];
    const float* ne_b2 = (const float*)d_in[7];
    const float* ee_w1 = (const float*)d_in[8];
    const float* ee_b1 = (const float*)d_in[9];
    const float* ee_w2 = (const float*)d_in[10];
    const float* ee_b2 = (const float*)d_in[11];
    const float* ml_w1 = (const float*)d_in[12];
    const float* ml_b1 = (const float*)d_in[13];
    const float* ml_w2 = (const float*)d_in[14];
    const float* ml_b2 = (const float*)d_in[15];
    const float* agg_w1 = (const float*)d_in[16];
    const float* agg_b1 = (const float*)d_in[17];
    const float* agg_w2 = (const float*)d_in[18];
    const float* agg_b2 = (const float*)d_in[19];

    const int NN = in_sizes[0] / 128;
    const int NE = in_sizes[1] / 2;
    const int n_layers = in_sizes[12] / (384 * 128);

    const size_t nchunk = (size_t)NN * 128;
    const size_t echunk = (size_t)NE * 128;
    if (ws_size < (4 * nchunk + echunk) * sizeof(float)) return;  // insufficient scratch

    float* ws = (float*)d_ws;
    float* node_emb = ws;
    float* new_emb  = node_emb + nchunk;
    float* P1       = new_emb + nchunk;
    float* P3       = P1 + nchunk;
    float* edge_emb = P3 + nchunk;
    float* out      = (float*)d_out;

    dim3 blk(256);
    fused_mlp_kernel<128><<<(NN + 63) / 64, blk, 0, stream>>>(
        node_f, ne_w1, ne_b1, ne_w2, ne_b2, node_emb, NN);
    fused_mlp_kernel<64><<<(NE + 63) / 64, blk, 0, stream>>>(
        edge_f, ee_w1, ee_b1, ee_w2, ee_b2, edge_emb, NE);

    for (int l = 0; l < n_layers; ++l) {
        const float* w1l = ml_w1 + (size_t)l * 384 * 128;
        gemm128_kernel<<<(NN + 63) / 64, blk, 0, stream>>>(
            node_emb, w1l, nullptr, P1, NN);
        gemm128_kernel<<<(NN + 63) / 64, blk, 0, stream>>>(
            node_emb, w1l + 256 * 128, nullptr, P3, NN);
        hipMemcpyAsync(new_emb, node_emb, nchunk * sizeof(float),
                       hipMemcpyDeviceToDevice, stream);
        message_kernel<<<(NE + 31) / 32, blk, 0, stream>>>(
            edge_emb, P1, P3, edge_list, w1l + 128 * 128, ml_b1 + (size_t)l * 128,
            ml_w2 + (size_t)l * 128 * 128, ml_b2 + (size_t)l * 128, new_emb, NE);
        float* dst = (l == n_layers - 1) ? out : node_emb;
        fused_mlp_kernel<128><<<(NN + 63) / 64, blk, 0, stream>>>(
            new_emb, agg_w1, agg_b1, agg_w2, agg_b2, dst, NN);
    }
}

// Round 2
// 1739.130 us; speedup vs baseline: 3.8226x; 3.8226x over previous
//
#include <hip/hip_runtime.h>

typedef float fx4 __attribute__((ext_vector_type(4)));
typedef unsigned short us4 __attribute__((ext_vector_type(4)));

static __device__ __forceinline__ fx4 ld4(const float* p) {
    return *reinterpret_cast<const fx4*>(p);
}
static __device__ __forceinline__ void st4(float* p, fx4 v) {
    *reinterpret_cast<fx4*>(p) = v;
}
static __device__ __forceinline__ fx4 relu4(fx4 v) {
    fx4 r;
    #pragma unroll
    for (int j = 0; j < 4; ++j) r[j] = fmaxf(v[j], 0.0f);
    return r;
}
static __device__ __forceinline__ fx4 ldbf4(const unsigned short* p) {
    us4 u = *reinterpret_cast<const us4*>(p);
    fx4 f;
    #pragma unroll
    for (int j = 0; j < 4; ++j) {
        union { unsigned int i; float f; } x;
        x.i = ((unsigned int)u[j]) << 16;
        f[j] = x.f;
    }
    return f;
}
static __device__ __forceinline__ void stbf4(unsigned short* p, fx4 v) {
    us4 u;
    #pragma unroll
    for (int j = 0; j < 4; ++j) {
        union { float f; unsigned int i; } x;
        x.f = v[j];
        unsigned int r = x.i + 0x7FFF + ((x.i >> 16) & 1);   // RNE
        u[j] = (unsigned short)(r >> 16);
    }
    *reinterpret_cast<us4*>(p) = u;
}

// 64-row x 128-col tile matmul: acc[4][2] (4 rows x 8 cols per thread).
template <int K, int LDA>
static __device__ __forceinline__ void mm64(const float* A, const float* __restrict__ W,
                                            int ty, int tx, fx4 acc[4][2]) {
    #pragma unroll
    for (int r = 0; r < 4; ++r) { acc[r][0] = 0.f; acc[r][1] = 0.f; }
    for (int k = 0; k < K; k += 4) {
        fx4 xr[4];
        #pragma unroll
        for (int r = 0; r < 4; ++r) xr[r] = ld4(A + (ty * 4 + r) * LDA + k);
        #pragma unroll
        for (int kk = 0; kk < 4; ++kk) {
            fx4 wa = ld4(W + (size_t)(k + kk) * 128 + tx * 8);
            fx4 wb = ld4(W + (size_t)(k + kk) * 128 + tx * 8 + 4);
            #pragma unroll
            for (int r = 0; r < 4; ++r) {
                acc[r][0] += xr[r][kk] * wa;
                acc[r][1] += xr[r][kk] * wb;
            }
        }
    }
}

template <int K1, bool OUT_BF16>
__global__ __launch_bounds__(256) void fused_mlp_kernel(
    const float* __restrict__ X, const float* __restrict__ W1,
    const float* __restrict__ b1, const float* __restrict__ W2,
    const float* __restrict__ b2, void* __restrict__ OutV, int M)
{
    constexpr int L1 = K1 + 4;
    __shared__ float Xs[64 * L1];
    __shared__ float Hs[64 * 132];
    const int tid = threadIdx.x;
    const int row0 = blockIdx.x * 64;
    constexpr int RP = K1 / 4;

    for (int i = tid; i < 64 * RP; i += 256) {
        int r = i / RP, c = (i % RP) * 4;
        fx4 v = {0.f, 0.f, 0.f, 0.f};
        int gr = row0 + r;
        if (gr < M) v = ld4(X + (size_t)gr * K1 + c);
        st4(&Xs[r * L1 + c], v);
    }
    __syncthreads();

    const int ty = tid >> 4, tx = tid & 15;
    fx4 acc[4][2];
    mm64<K1, L1>(Xs, W1, ty, tx, acc);
    {
        fx4 ba = ld4(b1 + tx * 8), bb = ld4(b1 + tx * 8 + 4);
        #pragma unroll
        for (int r = 0; r < 4; ++r) {
            st4(&Hs[(ty * 4 + r) * 132 + tx * 8], relu4(acc[r][0] + ba));
            st4(&Hs[(ty * 4 + r) * 132 + tx * 8 + 4], relu4(acc[r][1] + bb));
        }
    }
    __syncthreads();

    fx4 acc2[4][2];
    mm64<128, 132>(Hs, W2, ty, tx, acc2);
    {
        fx4 ba = ld4(b2 + tx * 8), bb = ld4(b2 + tx * 8 + 4);
        #pragma unroll
        for (int r = 0; r < 4; ++r) {
            int gr = row0 + ty * 4 + r;
            if (gr >= M) continue;
            fx4 o0 = acc2[r][0] + ba, o1 = acc2[r][1] + bb;
            if (OUT_BF16) {
                unsigned short* Out = (unsigned short*)OutV;
                stbf4(Out + (size_t)gr * 128 + tx * 8, o0);
                stbf4(Out + (size_t)gr * 128 + tx * 8 + 4, o1);
            } else {
                float* Out = (float*)OutV;
                st4(Out + (size_t)gr * 128 + tx * 8, o0);
                st4(Out + (size_t)gr * 128 + tx * 8 + 4, o1);
            }
        }
    }
}

__global__ __launch_bounds__(256) void gemm128_kernel(
    const float* __restrict__ X, const float* __restrict__ W,
    float* __restrict__ Out, int M)
{
    __shared__ float Xs[64 * 132];
    const int tid = threadIdx.x;
    const int row0 = blockIdx.x * 64;

    for (int i = tid; i < 64 * 32; i += 256) {
        int r = i >> 5, c = (i & 31) * 4;
        fx4 v = {0.f, 0.f, 0.f, 0.f};
        int gr = row0 + r;
        if (gr < M) v = ld4(X + (size_t)gr * 128 + c);
        st4(&Xs[r * 132 + c], v);
    }
    __syncthreads();

    const int ty = tid >> 4, tx = tid & 15;
    fx4 acc[4][2];
    mm64<128, 132>(Xs, W, ty, tx, acc);
    #pragma unroll
    for (int r = 0; r < 4; ++r) {
        int gr = row0 + ty * 4 + r;
        if (gr < M) {
            st4(Out + (size_t)gr * 128 + tx * 8, acc[r][0]);
            st4(Out + (size_t)gr * 128 + tx * 8 + 4, acc[r][1]);
        }
    }
}

__global__ __launch_bounds__(256) void gemm_ep_kernel(
    const unsigned short* __restrict__ X, const float* __restrict__ W,
    const float* __restrict__ bias, unsigned short* __restrict__ Out, int M)
{
    __shared__ float Xs[64 * 132];
    const int tid = threadIdx.x;
    const int row0 = blockIdx.x * 64;

    for (int i = tid; i < 64 * 32; i += 256) {
        int r = i >> 5, c = (i & 31) * 4;
        fx4 v = {0.f, 0.f, 0.f, 0.f};
        int gr = row0 + r;
        if (gr < M) v = ldbf4(X + (size_t)gr * 128 + c);
        st4(&Xs[r * 132 + c], v);
    }
    __syncthreads();

    const int ty = tid >> 4, tx = tid & 15;
    fx4 acc[4][2];
    mm64<128, 132>(Xs, W, ty, tx, acc);
    fx4 ba = ld4(bias + tx * 8), bb = ld4(bias + tx * 8 + 4);
    #pragma unroll
    for (int r = 0; r < 4; ++r) {
        int gr = row0 + ty * 4 + r;
        if (gr < M) {
            stbf4(Out + (size_t)gr * 128 + tx * 8, acc[r][0] + ba);
            stbf4(Out + (size_t)gr * 128 + tx * 8 + 4, acc[r][1] + bb);
        }
    }
}

__global__ __launch_bounds__(256) void csr_hist_kernel(
    const int* __restrict__ el, int* __restrict__ cnt, int NE)
{
    int e = blockIdx.x * 256 + threadIdx.x;
    if (e < NE) {
        atomicAdd(&cnt[el[2 * (size_t)e + 1]], 1);
        atomicAdd(&cnt[el[2 * (size_t)e]], 1);
    }
}

__global__ __launch_bounds__(256) void csr_scan_kernel(
    const int* __restrict__ cnt, int* __restrict__ startp, int NN)
{
    __shared__ int part[256];
    const int t = threadIdx.x;
    const int chunk = (NN + 255) / 256;
    const int lo = t * chunk;
    const int hi = min(lo + chunk, NN);
    int s = 0;
    for (int i = lo; i < hi; ++i) s += cnt[i];
    part[t] = s;
    __syncthreads();
    for (int off = 1; off < 256; off <<= 1) {
        int u = (t >= off) ? part[t - off] : 0;
        __syncthreads();
        part[t] += u;
        __syncthreads();
    }
    int run = part[t] - s;
    for (int i = lo; i < hi; ++i) { startp[i] = run; run += cnt[i]; }
    if (t == 255) startp[NN] = part[255];
}

__global__ __launch_bounds__(256) void csr_fill_kernel(
    const int* __restrict__ el, const int* __restrict__ startp,
    int* __restrict__ cursor, int2* __restrict__ inc, int NE)
{
    int e = blockIdx.x * 256 + threadIdx.x;
    if (e < NE) {
        int s = el[2 * (size_t)e], d = el[2 * (size_t)e + 1];
        int p = startp[d] + atomicAdd(&cursor[d], 1);
        inc[p] = make_int2(e, s);
        int q = startp[s] + atomicAdd(&cursor[s], 1);
        inc[q] = make_int2(e, d);
    }
}

__global__ __launch_bounds__(256) void gather_agg_kernel(
    const float* __restrict__ node_emb, const float* __restrict__ P1,
    const float* __restrict__ P3, const unsigned short* __restrict__ Ep,
    const int2* __restrict__ inc, const int* __restrict__ startp,
    const float* __restrict__ W2, const float* __restrict__ b2,
    const float* __restrict__ aw1, const float* __restrict__ ab1,
    const float* __restrict__ aw2, const float* __restrict__ ab2,
    float* __restrict__ Out, int M)
{
    __shared__ float Ss[64 * 132];
    __shared__ float Hs[64 * 132];
    const int tid = threadIdx.x;
    const int row0 = blockIdx.x * 64;

    for (int i = tid; i < 64 * 32; i += 256) {
        int r = i >> 5, c = (i & 31) * 4;
        int n = row0 + r;
        fx4 s = {0.f, 0.f, 0.f, 0.f};
        if (n < M) {
            fx4 p3 = ld4(P3 + (size_t)n * 128 + c);
            int j0 = startp[n], j1 = startp[n + 1];
            for (int j = j0; j < j1; ++j) {
                int2 io = inc[j];
                fx4 p1 = ld4(P1 + (size_t)io.y * 128 + c);
                fx4 ep = ldbf4(Ep + (size_t)io.x * 128 + c);
                s += relu4(p1 + ep + p3);
            }
        }
        st4(&Ss[r * 132 + c], s);
    }
    __syncthreads();

    const int ty = tid >> 4, tx = tid & 15;

    {
        fx4 acc[4][2];
        mm64<128, 132>(Ss, W2, ty, tx, acc);
        fx4 ba = ld4(b2 + tx * 8), bb = ld4(b2 + tx * 8 + 4);
        #pragma unroll
        for (int r = 0; r < 4; ++r) {
            int row = ty * 4 + r;
            int n = row0 + row;
            fx4 o0 = {0.f, 0.f, 0.f, 0.f}, o1 = {0.f, 0.f, 0.f, 0.f};
            if (n < M) {
                float deg = (float)(startp[n + 1] - startp[n]);
                o0 = ld4(node_emb + (size_t)n * 128 + tx * 8) + acc[r][0] + ba * deg;
                o1 = ld4(node_emb + (size_t)n * 128 + tx * 8 + 4) + acc[r][1] + bb * deg;
            }
            st4(&Hs[row * 132 + tx * 8], o0);
            st4(&Hs[row * 132 + tx * 8 + 4], o1);
        }
    }
    __syncthreads();

    {
        fx4 acc[4][2];
        mm64<128, 132>(Hs, aw1, ty, tx, acc);
        fx4 ba = ld4(ab1 + tx * 8), bb = ld4(ab1 + tx * 8 + 4);
        #pragma unroll
        for (int r = 0; r < 4; ++r) {
            st4(&Ss[(ty * 4 + r) * 132 + tx * 8], relu4(acc[r][0] + ba));
            st4(&Ss[(ty * 4 + r) * 132 + tx * 8 + 4], relu4(acc[r][1] + bb));
        }
    }
    __syncthreads();

    {
        fx4 acc[4][2];
        mm64<128, 132>(Ss, aw2, ty, tx, acc);
        fx4 ba = ld4(ab2 + tx * 8), bb = ld4(ab2 + tx * 8 + 4);
        #pragma unroll
        for (int r = 0; r < 4; ++r) {
            int gr = row0 + ty * 4 + r;
            if (gr < M) {
                st4(Out + (size_t)gr * 128 + tx * 8, acc[r][0] + ba);
                st4(Out + (size_t)gr * 128 + tx * 8 + 4, acc[r][1] + bb);
            }
        }
    }
}

extern "C" void kernel_launch(void* const* d_in, const int* in_sizes, int n_in,
                              void* d_out, int out_size, void* d_ws, size_t ws_size,
                              hipStream_t stream) {
    const float* node_f    = (const float*)d_in[0];
    const int*   edge_list = (const int*)d_in[1];
    const float* edge_f    = (const float*)d_in[2];
    const float* ne_w1 = (const float*)d_in[4];
    const float* ne_b1 = (const float*)d_in[5];
    const float* ne_w2 = (const float*)d_in[6];
    const float* ne_b2 = (const float*)d_in[7];
    const float* ee_w1 = (const float*)d_in[8];
    const float* ee_b1 = (const float*)d_in[9];
    const float* ee_w2 = (const float*)d_in[10];
    const float* ee_b2 = (const float*)d_in[11];
    const float* ml_w1 = (const float*)d_in[12];
    const float* ml_b1 = (const float*)d_in[13];
    const float* ml_w2 = (const float*)d_in[14];
    const float* ml_b2 = (const float*)d_in[15];
    const float* agg_w1 = (const float*)d_in[16];
    const float* agg_b1 = (const float*)d_in[17];
    const float* agg_w2 = (const float*)d_in[18];
    const float* agg_b2 = (const float*)d_in[19];

    const int NN = in_sizes[0] / 128;
    const int NE = in_sizes[1] / 2;
    const int n_layers = in_sizes[12] / (384 * 128);

    const size_t nchunk = (size_t)NN * 128;
    const size_t echunk = (size_t)NE * 128;

    float* node_emb = (float*)d_ws;
    float* P1 = node_emb + nchunk;
    float* P3 = P1 + nchunk;
    unsigned short* edge_emb = (unsigned short*)(P3 + nchunk);
    unsigned short* Ep = edge_emb + echunk;
    int* cnt = (int*)(Ep + echunk);
    int* startp = cnt + NN;
    uintptr_t inc_addr = ((uintptr_t)(startp + NN + 1) + 15) & ~(uintptr_t)15;
    int2* inc = (int2*)inc_addr;
    size_t need = (inc_addr + 2 * (size_t)NE * sizeof(int2)) - (uintptr_t)d_ws;
    if (ws_size < need) return;

    dim3 blk(256);
    const int gN = (NN + 63) / 64;
    const int gE64 = (NE + 63) / 64;
    const int gE256 = (NE + 255) / 256;

    fused_mlp_kernel<128, false><<<gN, blk, 0, stream>>>(
        node_f, ne_w1, ne_b1, ne_w2, ne_b2, node_emb, NN);
    fused_mlp_kernel<64, true><<<gE64, blk, 0, stream>>>(
        edge_f, ee_w1, ee_b1, ee_w2, ee_b2, edge_emb, NE);

    hipMemsetAsync(cnt, 0, (size_t)NN * sizeof(int), stream);
    csr_hist_kernel<<<gE256, blk, 0, stream>>>(edge_list, cnt, NE);
    csr_scan_kernel<<<1, blk, 0, stream>>>(cnt, startp, NN);
    hipMemsetAsync(cnt, 0, (size_t)NN * sizeof(int), stream);
    csr_fill_kernel<<<gE256, blk, 0, stream>>>(edge_list, startp, cnt, inc, NE);

    float* out = (float*)d_out;
    for (int l = 0; l < n_layers; ++l) {
        const float* w1l = ml_w1 + (size_t)l * 384 * 128;
        gemm128_kernel<<<gN, blk, 0, stream>>>(node_emb, w1l, P1, NN);
        gemm128_kernel<<<gN, blk, 0, stream>>>(node_emb, w1l + 256 * 128, P3, NN);
        gemm_ep_kernel<<<gE64, blk, 0, stream>>>(
            edge_emb, w1l + 128 * 128, ml_b1 + (size_t)l * 128, Ep, NE);
        float* dst = (l == n_layers - 1) ? out : node_emb;
        gather_agg_kernel<<<gN, blk, 0, stream>>>(
            node_emb, P1, P3, Ep, inc, startp,
            ml_w2 + (size_t)l * 128 * 128, ml_b2 + (size_t)l * 128,
            agg_w1, agg_b1, agg_w2, agg_b2, dst, NN);
    }
}

// Round 3
// 881.644 us; speedup vs baseline: 7.5405x; 1.9726x over previous
//
#include <hip/hip_runtime.h>

typedef float fx4 __attribute__((ext_vector_type(4)));
typedef float f32x4 __attribute__((ext_vector_type(4)));
typedef unsigned short us8 __attribute__((ext_vector_type(8)));
typedef __bf16 bf8 __attribute__((ext_vector_type(8)));

static __device__ __forceinline__ fx4 ld4(const float* p) {
    return *reinterpret_cast<const fx4*>(p);
}
static __device__ __forceinline__ void st4(float* p, fx4 v) {
    *reinterpret_cast<fx4*>(p) = v;
}
static __device__ __forceinline__ unsigned short f2bf(float f) {
    union { float f; unsigned int i; } x; x.f = f;
    unsigned int r = x.i + 0x7FFF + ((x.i >> 16) & 1);   // RNE
    return (unsigned short)(r >> 16);
}
static __device__ __forceinline__ float bf2f(unsigned int u) {
    union { unsigned int i; float f; } x; x.i = u << 16; return x.f;
}

static __device__ __forceinline__ f32x4 mfma16(us8 a, us8 b, f32x4 c) {
    return __builtin_amdgcn_mfma_f32_16x16x32_bf16(
        __builtin_bit_cast(bf8, a), __builtin_bit_cast(bf8, b), c, 0, 0, 0);
}

// ---------------- MFMA GEMM: Out[M][128] = A[M][K1] @ W[K1][128] (+epilogue) ---
// Wt is transposed bf16 weight: Wt[n][k] = W[k][n].
// XMODE: out = acc + resid[r][col] + deg[r]*bias[col]  (no plain bias, no relu)
template <int K1, bool AF32, bool BIAS, bool RELU, bool OUTF, bool OUTB, bool XMODE>
__global__ __launch_bounds__(256) void mfma_gemm(
    const void* __restrict__ Av, const unsigned short* __restrict__ Wt,
    const float* __restrict__ bias,
    float* __restrict__ outF, unsigned short* __restrict__ outB,
    const float* __restrict__ resid, const int* __restrict__ startp, int M)
{
    constexpr int KP = K1 + 8;                     // padded LDS row, bf16 units
    __shared__ unsigned short Ws[128 * KP];
    const int tid = threadIdx.x;
    const int lane = tid & 63;
    const int wv = tid >> 6;
    const int row0 = blockIdx.x * 128 + wv * 32;

    constexpr int C8 = K1 / 8;
    for (int i = tid; i < 128 * C8; i += 256) {
        int r = i / C8, c = (i % C8) * 8;
        *reinterpret_cast<us8*>(&Ws[r * KP + c]) =
            *reinterpret_cast<const us8*>(&Wt[r * K1 + c]);
    }
    __syncthreads();

    const int ar = lane & 15;            // A row / B col within 16-tile
    const int ak = (lane >> 4) * 8;      // k offset within 32-k step

    f32x4 acc[2][8];
    #pragma unroll
    for (int m = 0; m < 2; ++m)
        #pragma unroll
        for (int nt = 0; nt < 8; ++nt) acc[m][nt] = {0.f, 0.f, 0.f, 0.f};

    #pragma unroll
    for (int kk = 0; kk < K1 / 32; ++kk) {
        us8 a[2];
        #pragma unroll
        for (int m = 0; m < 2; ++m) {
            int row = row0 + m * 16 + ar;
            us8 t = 0;
            if (row < M) {
                if (AF32) {
                    const float* ap = (const float*)Av + (size_t)row * K1 + kk * 32 + ak;
                    fx4 x0 = ld4(ap), x1 = ld4(ap + 4);
                    #pragma unroll
                    for (int j = 0; j < 4; ++j) {
                        t[j] = f2bf(x0[j]);
                        t[4 + j] = f2bf(x1[j]);
                    }
                } else {
                    t = *reinterpret_cast<const us8*>(
                        (const unsigned short*)Av + (size_t)row * K1 + kk * 32 + ak);
                }
            }
            a[m] = t;
        }
        #pragma unroll
        for (int nt = 0; nt < 8; ++nt) {
            us8 b = *reinterpret_cast<const us8*>(&Ws[(nt * 16 + ar) * KP + kk * 32 + ak]);
            acc[0][nt] = mfma16(a[0], b, acc[0][nt]);
            acc[1][nt] = mfma16(a[1], b, acc[1][nt]);
        }
    }

    const int crow = (lane >> 4) * 4;
    const int ccol = lane & 15;
    #pragma unroll
    for (int m = 0; m < 2; ++m) {
        int rbase = row0 + m * 16 + crow;
        float deg[4];
        if (XMODE) {
            #pragma unroll
            for (int i = 0; i < 4; ++i) {
                int r = rbase + i;
                deg[i] = (r < M) ? (float)(startp[r + 1] - startp[r]) : 0.f;
            }
        }
        #pragma unroll
        for (int nt = 0; nt < 8; ++nt) {
            int col = nt * 16 + ccol;
            float bc = BIAS ? bias[col] : 0.f;
            #pragma unroll
            for (int i = 0; i < 4; ++i) {
                int r = rbase + i;
                if (r >= M) continue;
                float o = acc[m][nt][i];
                if (XMODE) o += resid[(size_t)r * 128 + col] + deg[i] * bc;
                else if (BIAS) o += bc;
                if (RELU) o = fmaxf(o, 0.f);
                if (OUTF) outF[(size_t)r * 128 + col] = o;
                if (OUTB) outB[(size_t)r * 128 + col] = f2bf(o);
            }
        }
    }
}

// ---------------- fp32 helper GEMM for the tiny weight-fold (M=128) ----------
typedef float fx4b __attribute__((ext_vector_type(4)));
template <int DUMMY>
static __device__ __forceinline__ void mm64f(const float* A, const float* __restrict__ W,
                                             int ty, int tx, fx4 acc[4][2]) {
    #pragma unroll
    for (int r = 0; r < 4; ++r) { acc[r][0] = 0.f; acc[r][1] = 0.f; }
    for (int k = 0; k < 128; k += 4) {
        fx4 xr[4];
        #pragma unroll
        for (int r = 0; r < 4; ++r) xr[r] = ld4(A + (ty * 4 + r) * 132 + k);
        #pragma unroll
        for (int kk = 0; kk < 4; ++kk) {
            fx4 wa = ld4(W + (size_t)(k + kk) * 128 + tx * 8);
            fx4 wb = ld4(W + (size_t)(k + kk) * 128 + tx * 8 + 4);
            #pragma unroll
            for (int r = 0; r < 4; ++r) {
                acc[r][0] += xr[r][kk] * wa;
                acc[r][1] += xr[r][kk] * wb;
            }
        }
    }
}

__global__ __launch_bounds__(256) void gemm128_kernel(
    const float* __restrict__ X, const float* __restrict__ W,
    float* __restrict__ Out, int M)
{
    __shared__ float Xs[64 * 132];
    const int tid = threadIdx.x;
    const int row0 = blockIdx.x * 64;

    for (int i = tid; i < 64 * 32; i += 256) {
        int r = i >> 5, c = (i & 31) * 4;
        fx4 v = {0.f, 0.f, 0.f, 0.f};
        int gr = row0 + r;
        if (gr < M) v = ld4(X + (size_t)gr * 128 + c);
        st4(&Xs[r * 132 + c], v);
    }
    __syncthreads();

    const int ty = tid >> 4, tx = tid & 15;
    fx4 acc[4][2];
    mm64f<0>(Xs, W, ty, tx, acc);
    #pragma unroll
    for (int r = 0; r < 4; ++r) {
        int gr = row0 + ty * 4 + r;
        if (gr < M) {
            st4(Out + (size_t)gr * 128 + tx * 8, acc[r][0]);
            st4(Out + (size_t)gr * 128 + tx * 8 + 4, acc[r][1]);
        }
    }
}

// ---------------- weight prep ------------------------------------------------
struct TJob { const float* src; unsigned short* dst; int K; };
struct TJobs { TJob j[16]; };

__global__ __launch_bounds__(256) void transpose_kernel(TJobs jobs) {
    TJob t = jobs.j[blockIdx.x];
    int total = 128 * t.K;
    for (int i = threadIdx.x; i < total; i += 256) {
        int n = i / t.K, k = i - n * t.K;
        t.dst[(size_t)n * t.K + k] = f2bf(t.src[(size_t)k * 128 + n]);
    }
}

// bep[l][n] = ml_b1[l][n] + sum_k ee_b2[k] * W1b_l[k][n]
__global__ __launch_bounds__(128) void bep_kernel(
    const float* __restrict__ ee_b2, const float* __restrict__ ml_w1,
    const float* __restrict__ ml_b1, float* __restrict__ bep)
{
    int l = blockIdx.x, n = threadIdx.x;
    const float* W1b = ml_w1 + (size_t)l * 384 * 128 + 128 * 128;
    float s = ml_b1[(size_t)l * 128 + n];
    for (int k = 0; k < 128; ++k) s += ee_b2[k] * W1b[(size_t)k * 128 + n];
    bep[(size_t)l * 128 + n] = s;
}

// ---------------- CSR build --------------------------------------------------
__global__ __launch_bounds__(256) void csr_hist_kernel(
    const int* __restrict__ el, int* __restrict__ cnt, int NE)
{
    int e = blockIdx.x * 256 + threadIdx.x;
    if (e < NE) {
        atomicAdd(&cnt[el[2 * (size_t)e + 1]], 1);
        atomicAdd(&cnt[el[2 * (size_t)e]], 1);
    }
}

__global__ __launch_bounds__(256) void csr_scan_kernel(
    const int* __restrict__ cnt, int* __restrict__ startp, int NN)
{
    __shared__ int part[256];
    const int t = threadIdx.x;
    const int chunk = (NN + 255) / 256;
    const int lo = t * chunk;
    const int hi = min(lo + chunk, NN);
    int s = 0;
    for (int i = lo; i < hi; ++i) s += cnt[i];
    part[t] = s;
    __syncthreads();
    for (int off = 1; off < 256; off <<= 1) {
        int u = (t >= off) ? part[t - off] : 0;
        __syncthreads();
        part[t] += u;
        __syncthreads();
    }
    int run = part[t] - s;
    for (int i = lo; i < hi; ++i) { startp[i] = run; run += cnt[i]; }
    if (t == 255) startp[NN] = part[255];
}

// inc[pos] = 2*e + side; other endpoint = edge_list[inc[pos]]
__global__ __launch_bounds__(256) void csr_fill_kernel(
    const int* __restrict__ el, const int* __restrict__ startp,
    int* __restrict__ cursor, int* __restrict__ inc, int NE)
{
    int e = blockIdx.x * 256 + threadIdx.x;
    if (e < NE) {
        int s = el[2 * (size_t)e], d = el[2 * (size_t)e + 1];
        int p = startp[d] + atomicAdd(&cursor[d], 1);
        inc[p] = 2 * e;          // msg into d, other = el[2e] = s
        int q = startp[s] + atomicAdd(&cursor[s], 1);
        inc[q] = 2 * e + 1;      // msg into s, other = el[2e+1] = d
    }
}

// ---------------- gather: S[n] = sum_j relu(P1[o_j] + Ep[e_j] + P3[n]) -------
__global__ __launch_bounds__(256) void gather_kernel(
    const unsigned short* __restrict__ P1bf, const unsigned short* __restrict__ P3bf,
    const unsigned short* __restrict__ Ep, const int* __restrict__ inc,
    const int* __restrict__ startp, const int* __restrict__ edge_list,
    unsigned short* __restrict__ S, int M)
{
    const int lane = threadIdx.x & 63;
    const int n = blockIdx.x * 4 + (threadIdx.x >> 6);
    if (n >= M) return;
    const int c2 = lane * 2;

    unsigned int up3 = *reinterpret_cast<const unsigned int*>(&P3bf[(size_t)n * 128 + c2]);
    float p3a = bf2f(up3 & 0xffff), p3b = bf2f(up3 >> 16);
    float s0 = 0.f, s1 = 0.f;
    int j0 = startp[n], j1 = startp[n + 1];
    for (int j = j0; j < j1; ++j) {
        int idx = inc[j];
        int o = edge_list[idx];
        unsigned int up1 = *reinterpret_cast<const unsigned int*>(&P1bf[(size_t)o * 128 + c2]);
        unsigned int uep = *reinterpret_cast<const unsigned int*>(&Ep[(size_t)(idx >> 1) * 128 + c2]);
        s0 += fmaxf(p3a + bf2f(up1 & 0xffff) + bf2f(uep & 0xffff), 0.f);
        s1 += fmaxf(p3b + bf2f(up1 >> 16) + bf2f(uep >> 16), 0.f);
    }
    unsigned int pk = ((unsigned int)f2bf(s1) << 16) | (unsigned int)f2bf(s0);
    *reinterpret_cast<unsigned int*>(&S[(size_t)n * 128 + c2]) = pk;
}

// ---------------- host launch ------------------------------------------------
extern "C" void kernel_launch(void* const* d_in, const int* in_sizes, int n_in,
                              void* d_out, int out_size, void* d_ws, size_t ws_size,
                              hipStream_t stream) {
    const float* node_f    = (const float*)d_in[0];
    const int*   edge_list = (const int*)d_in[1];
    const float* edge_f    = (const float*)d_in[2];
    const float* ne_w1 = (const float*)d_in[4];
    const float* ne_b1 = (const float*)d_in[5];
    const float* ne_w2 = (const float*)d_in[6];
    const float* ne_b2 = (const float*)d_in[7];
    const float* ee_w1 = (const float*)d_in[8];
    const float* ee_b1 = (const float*)d_in[9];
    const float* ee_w2 = (const float*)d_in[10];
    const float* ee_b2 = (const float*)d_in[11];
    const float* ml_w1 = (const float*)d_in[12];
    const float* ml_b1 = (const float*)d_in[13];
    const float* ml_w2 = (const float*)d_in[14];
    const float* ml_b2 = (const float*)d_in[15];
    const float* agg_w1 = (const float*)d_in[16];
    const float* agg_b1 = (const float*)d_in[17];
    const float* agg_w2 = (const float*)d_in[18];
    const float* agg_b2 = (const float*)d_in[19];

    const int NN = in_sizes[0] / 128;
    const int NE = in_sizes[1] / 2;
    const int n_layers = in_sizes[12] / (384 * 128);

    // ---- workspace layout (256B-aligned blocks) ----
    char* p = (char*)d_ws;
    auto alloc = [&](size_t bytes) -> void* {
        void* r = (void*)p;
        p += (bytes + 255) & ~(size_t)255;
        return r;
    };
    float* node_emb = (float*)alloc((size_t)NN * 128 * 4);
    unsigned short* P1bf = (unsigned short*)alloc((size_t)NN * 128 * 2);
    unsigned short* P3bf = (unsigned short*)alloc((size_t)NN * 128 * 2);
    unsigned short* bufS = (unsigned short*)alloc((size_t)NN * 128 * 2);
    unsigned short* H_edge = (unsigned short*)alloc((size_t)NE * 128 * 2);
    unsigned short* Ep = (unsigned short*)alloc((size_t)NE * 128 * 2);
    unsigned short* ne_w1t = (unsigned short*)alloc(128 * 128 * 2);
    unsigned short* ne_w2t = (unsigned short*)alloc(128 * 128 * 2);
    unsigned short* ee_w1t = (unsigned short*)alloc(128 * 64 * 2);
    unsigned short* aw1t = (unsigned short*)alloc(128 * 128 * 2);
    unsigned short* aw2t = (unsigned short*)alloc(128 * 128 * 2);
    unsigned short* W1at[2], *W1ct[2], *W2t[2], *Wept[2];
    float* Wepf[2];
    for (int l = 0; l < 2; ++l) {
        W1at[l] = (unsigned short*)alloc(128 * 128 * 2);
        W1ct[l] = (unsigned short*)alloc(128 * 128 * 2);
        W2t[l]  = (unsigned short*)alloc(128 * 128 * 2);
        Wept[l] = (unsigned short*)alloc(128 * 128 * 2);
        Wepf[l] = (float*)alloc(128 * 128 * 4);
    }
    float* bep = (float*)alloc((size_t)2 * 128 * 4);
    int* cnt = (int*)alloc((size_t)NN * 4);
    int* startp = (int*)alloc((size_t)(NN + 1) * 4);
    int* inc = (int*)alloc((size_t)2 * NE * 4);
    size_t need = (size_t)(p - (char*)d_ws);
    if (ws_size < need) return;

    dim3 blk(256);
    const int gM_N = (NN + 127) / 128;    // MFMA grid, node-sized
    const int gM_E = (NE + 127) / 128;    // MFMA grid, edge-sized
    const int gE256 = (NE + 255) / 256;

    // ---- weight prep ----
    for (int l = 0; l < n_layers && l < 2; ++l) {
        const float* W1b = ml_w1 + (size_t)l * 384 * 128 + 128 * 128;
        gemm128_kernel<<<2, blk, 0, stream>>>(ee_w2, W1b, Wepf[l], 128);
    }
    {
        TJobs jobs{};
        int nj = 0;
        jobs.j[nj++] = {ne_w1, ne_w1t, 128};
        jobs.j[nj++] = {ne_w2, ne_w2t, 128};
        jobs.j[nj++] = {ee_w1, ee_w1t, 64};
        jobs.j[nj++] = {agg_w1, aw1t, 128};
        jobs.j[nj++] = {agg_w2, aw2t, 128};
        for (int l = 0; l < n_layers && l < 2; ++l) {
            jobs.j[nj++] = {ml_w1 + (size_t)l * 384 * 128, W1at[l], 128};
            jobs.j[nj++] = {ml_w1 + (size_t)l * 384 * 128 + 256 * 128, W1ct[l], 128};
            jobs.j[nj++] = {ml_w2 + (size_t)l * 128 * 128, W2t[l], 128};
            jobs.j[nj++] = {Wepf[l], Wept[l], 128};
        }
        transpose_kernel<<<nj, blk, 0, stream>>>(jobs);
    }
    bep_kernel<<<n_layers, 128, 0, stream>>>(ee_b2, ml_w1, ml_b1, bep);

    // ---- encoders ----
    // Hn = relu(node_f @ ne_w1 + ne_b1)  -> bufS (bf16)
    mfma_gemm<128, true, true, true, false, true, false><<<gM_N, blk, 0, stream>>>(
        node_f, ne_w1t, ne_b1, nullptr, bufS, nullptr, nullptr, NN);
    // node_emb = Hn @ ne_w2 + ne_b2  -> f32
    mfma_gemm<128, false, true, false, true, false, false><<<gM_N, blk, 0, stream>>>(
        bufS, ne_w2t, ne_b2, node_emb, nullptr, nullptr, nullptr, NN);
    // H_edge = relu(edge_f @ ee_w1 + ee_b1) -> bf16
    mfma_gemm<64, true, true, true, false, true, false><<<gM_E, blk, 0, stream>>>(
        edge_f, ee_w1t, ee_b1, nullptr, H_edge, nullptr, nullptr, NE);

    // ---- CSR incidence ----
    hipMemsetAsync(cnt, 0, (size_t)NN * sizeof(int), stream);
    csr_hist_kernel<<<gE256, blk, 0, stream>>>(edge_list, cnt, NE);
    csr_scan_kernel<<<1, blk, 0, stream>>>(cnt, startp, NN);
    hipMemsetAsync(cnt, 0, (size_t)NN * sizeof(int), stream);
    csr_fill_kernel<<<gE256, blk, 0, stream>>>(edge_list, startp, cnt, inc, NE);

    float* out = (float*)d_out;
    for (int l = 0; l < n_layers && l < 2; ++l) {
        // P1 = node_emb @ W1a   (bf16 out)
        mfma_gemm<128, true, false, false, false, true, false><<<gM_N, blk, 0, stream>>>(
            node_emb, W1at[l], nullptr, nullptr, P1bf, nullptr, nullptr, NN);
        // P3 = node_emb @ W1c
        mfma_gemm<128, true, false, false, false, true, false><<<gM_N, blk, 0, stream>>>(
            node_emb, W1ct[l], nullptr, nullptr, P3bf, nullptr, nullptr, NN);
        // Ep = H_edge @ Wep + bep   (bf16 out)
        mfma_gemm<128, false, true, false, false, true, false><<<gM_E, blk, 0, stream>>>(
            H_edge, Wept[l], bep + (size_t)l * 128, nullptr, Ep, nullptr, nullptr, NE);
        // S = gather-sum of relu'd hiddens -> bufS
        gather_kernel<<<(NN + 3) / 4, blk, 0, stream>>>(
            P1bf, P3bf, Ep, inc, startp, edge_list, bufS, NN);
        // X = node_emb + S@W2 + deg*b2 -> P1bf (bf16)
        mfma_gemm<128, false, true, false, false, true, true><<<gM_N, blk, 0, stream>>>(
            bufS, W2t[l], ml_b2 + (size_t)l * 128, nullptr, P1bf, node_emb, startp, NN);
        // H1 = relu(X @ aw1 + ab1) -> bufS
        mfma_gemm<128, false, true, true, false, true, false><<<gM_N, blk, 0, stream>>>(
            P1bf, aw1t, agg_b1, nullptr, bufS, nullptr, nullptr, NN);
        // out = H1 @ aw2 + ab2 -> f32 (node_emb or d_out)
        float* dst = (l == n_layers - 1) ? out : node_emb;
        mfma_gemm<128, false, true, false, true, false, false><<<gM_N, blk, 0, stream>>>(
            bufS, aw2t, agg_b2, dst, nullptr, nullptr, nullptr, NN);
    }
}

// Round 4
// 736.912 us; speedup vs baseline: 9.0215x; 1.1964x over previous
//
#include <hip/hip_runtime.h>

typedef float fx4 __attribute__((ext_vector_type(4)));
typedef float f32x4 __attribute__((ext_vector_type(4)));
typedef unsigned short us8 __attribute__((ext_vector_type(8)));
typedef __bf16 bf8 __attribute__((ext_vector_type(8)));

static __device__ __forceinline__ fx4 ld4(const float* p) {
    return *reinterpret_cast<const fx4*>(p);
}
static __device__ __forceinline__ void st4(float* p, fx4 v) {
    *reinterpret_cast<fx4*>(p) = v;
}
static __device__ __forceinline__ unsigned short f2bf(float f) {
    union { float f; unsigned int i; } x; x.f = f;
    unsigned int r = x.i + 0x7FFF + ((x.i >> 16) & 1);   // RNE
    return (unsigned short)(r >> 16);
}
static __device__ __forceinline__ float bf2f(unsigned int u) {
    union { unsigned int i; float f; } x; x.i = u << 16; return x.f;
}

static __device__ __forceinline__ f32x4 mfma16(us8 a, us8 b, f32x4 c) {
    return __builtin_amdgcn_mfma_f32_16x16x32_bf16(
        __builtin_bit_cast(bf8, a), __builtin_bit_cast(bf8, b), c, 0, 0, 0);
}

// ---------------- MFMA GEMM: Out[M][128] = A[M][K1] @ W[K1][128] (+epilogue) ---
// Wt is transposed bf16 weight: Wt[n][k] = W[k][n].
// XMODE: out = acc + resid[r][col] + deg[r]*bias[col]  (no plain bias, no relu)
template <int K1, bool AF32, bool BIAS, bool RELU, bool OUTF, bool OUTB, bool XMODE>
__global__ __launch_bounds__(256) void mfma_gemm(
    const void* __restrict__ Av, const unsigned short* __restrict__ Wt,
    const float* __restrict__ bias,
    float* __restrict__ outF, unsigned short* __restrict__ outB,
    const float* __restrict__ resid, const int* __restrict__ startp, int M)
{
    constexpr int KP = K1 + 8;                     // padded LDS row, bf16 units
    __shared__ unsigned short Ws[128 * KP];
    const int tid = threadIdx.x;
    const int lane = tid & 63;
    const int wv = tid >> 6;
    const int row0 = blockIdx.x * 128 + wv * 32;

    constexpr int C8 = K1 / 8;
    for (int i = tid; i < 128 * C8; i += 256) {
        int r = i / C8, c = (i % C8) * 8;
        *reinterpret_cast<us8*>(&Ws[r * KP + c]) =
            *reinterpret_cast<const us8*>(&Wt[r * K1 + c]);
    }
    __syncthreads();

    const int ar = lane & 15;            // A row / B col within 16-tile
    const int ak = (lane >> 4) * 8;      // k offset within 32-k step

    f32x4 acc[2][8];
    #pragma unroll
    for (int m = 0; m < 2; ++m)
        #pragma unroll
        for (int nt = 0; nt < 8; ++nt) acc[m][nt] = {0.f, 0.f, 0.f, 0.f};

    #pragma unroll
    for (int kk = 0; kk < K1 / 32; ++kk) {
        us8 a[2];
        #pragma unroll
        for (int m = 0; m < 2; ++m) {
            int row = row0 + m * 16 + ar;
            us8 t = 0;
            if (row < M) {
                if (AF32) {
                    const float* ap = (const float*)Av + (size_t)row * K1 + kk * 32 + ak;
                    fx4 x0 = ld4(ap), x1 = ld4(ap + 4);
                    #pragma unroll
                    for (int j = 0; j < 4; ++j) {
                        t[j] = f2bf(x0[j]);
                        t[4 + j] = f2bf(x1[j]);
                    }
                } else {
                    t = *reinterpret_cast<const us8*>(
                        (const unsigned short*)Av + (size_t)row * K1 + kk * 32 + ak);
                }
            }
            a[m] = t;
        }
        #pragma unroll
        for (int nt = 0; nt < 8; ++nt) {
            us8 b = *reinterpret_cast<const us8*>(&Ws[(nt * 16 + ar) * KP + kk * 32 + ak]);
            acc[0][nt] = mfma16(a[0], b, acc[0][nt]);
            acc[1][nt] = mfma16(a[1], b, acc[1][nt]);
        }
    }

    const int crow = (lane >> 4) * 4;
    const int ccol = lane & 15;
    #pragma unroll
    for (int m = 0; m < 2; ++m) {
        int rbase = row0 + m * 16 + crow;
        float deg[4];
        if (XMODE) {
            #pragma unroll
            for (int i = 0; i < 4; ++i) {
                int r = rbase + i;
                deg[i] = (r < M) ? (float)(startp[r + 1] - startp[r]) : 0.f;
            }
        }
        #pragma unroll
        for (int nt = 0; nt < 8; ++nt) {
            int col = nt * 16 + ccol;
            float bc = BIAS ? bias[col] : 0.f;
            #pragma unroll
            for (int i = 0; i < 4; ++i) {
                int r = rbase + i;
                if (r >= M) continue;
                float o = acc[m][nt][i];
                if (XMODE) o += resid[(size_t)r * 128 + col] + deg[i] * bc;
                else if (BIAS) o += bc;
                if (RELU) o = fmaxf(o, 0.f);
                if (OUTF) outF[(size_t)r * 128 + col] = o;
                if (OUTB) outB[(size_t)r * 128 + col] = f2bf(o);
            }
        }
    }
}

// ---- dual-output GEMM: [P1|P3] = A[M][128] @ [W1a|W1c]; Wt is 256 rows x 128k
__global__ __launch_bounds__(256) void mfma_gemm_dual(
    const float* __restrict__ A, const unsigned short* __restrict__ Wt,
    unsigned short* __restrict__ out1, unsigned short* __restrict__ out2, int M)
{
    constexpr int KP = 136;
    __shared__ unsigned short Ws[256 * KP];
    const int tid = threadIdx.x;
    const int lane = tid & 63;
    const int wv = tid >> 6;
    const int row0 = blockIdx.x * 128 + wv * 32;

    for (int i = tid; i < 256 * 16; i += 256) {
        int r = i >> 4, c = (i & 15) * 8;
        *reinterpret_cast<us8*>(&Ws[r * KP + c]) =
            *reinterpret_cast<const us8*>(&Wt[r * 128 + c]);
    }
    __syncthreads();

    const int ar = lane & 15;
    const int ak = (lane >> 4) * 8;

    f32x4 acc[2][16];
    #pragma unroll
    for (int m = 0; m < 2; ++m)
        #pragma unroll
        for (int nt = 0; nt < 16; ++nt) acc[m][nt] = {0.f, 0.f, 0.f, 0.f};

    #pragma unroll
    for (int kk = 0; kk < 4; ++kk) {
        us8 a[2];
        #pragma unroll
        for (int m = 0; m < 2; ++m) {
            int row = row0 + m * 16 + ar;
            us8 t = 0;
            if (row < M) {
                const float* ap = A + (size_t)row * 128 + kk * 32 + ak;
                fx4 x0 = ld4(ap), x1 = ld4(ap + 4);
                #pragma unroll
                for (int j = 0; j < 4; ++j) {
                    t[j] = f2bf(x0[j]);
                    t[4 + j] = f2bf(x1[j]);
                }
            }
            a[m] = t;
        }
        #pragma unroll
        for (int nt = 0; nt < 16; ++nt) {
            us8 b = *reinterpret_cast<const us8*>(&Ws[(nt * 16 + ar) * KP + kk * 32 + ak]);
            acc[0][nt] = mfma16(a[0], b, acc[0][nt]);
            acc[1][nt] = mfma16(a[1], b, acc[1][nt]);
        }
    }

    const int crow = (lane >> 4) * 4;
    const int ccol = lane & 15;
    #pragma unroll
    for (int m = 0; m < 2; ++m) {
        int rbase = row0 + m * 16 + crow;
        #pragma unroll
        for (int nt = 0; nt < 16; ++nt) {
            int col = nt * 16 + ccol;
            unsigned short* o = (nt < 8) ? out1 : out2;
            int oc = col & 127;
            #pragma unroll
            for (int i = 0; i < 4; ++i) {
                int r = rbase + i;
                if (r >= M) continue;
                o[(size_t)r * 128 + oc] = f2bf(acc[m][nt][i]);
            }
        }
    }
}

// ---------------- fp32 helper GEMM for the tiny weight-fold (M=128) ----------
template <int DUMMY>
static __device__ __forceinline__ void mm64f(const float* A, const float* __restrict__ W,
                                             int ty, int tx, fx4 acc[4][2]) {
    #pragma unroll
    for (int r = 0; r < 4; ++r) { acc[r][0] = 0.f; acc[r][1] = 0.f; }
    for (int k = 0; k < 128; k += 4) {
        fx4 xr[4];
        #pragma unroll
        for (int r = 0; r < 4; ++r) xr[r] = ld4(A + (ty * 4 + r) * 132 + k);
        #pragma unroll
        for (int kk = 0; kk < 4; ++kk) {
            fx4 wa = ld4(W + (size_t)(k + kk) * 128 + tx * 8);
            fx4 wb = ld4(W + (size_t)(k + kk) * 128 + tx * 8 + 4);
            #pragma unroll
            for (int r = 0; r < 4; ++r) {
                acc[r][0] += xr[r][kk] * wa;
                acc[r][1] += xr[r][kk] * wb;
            }
        }
    }
}

__global__ __launch_bounds__(256) void gemm128_kernel(
    const float* __restrict__ X, const float* __restrict__ W,
    float* __restrict__ Out, int M)
{
    __shared__ float Xs[64 * 132];
    const int tid = threadIdx.x;
    const int row0 = blockIdx.x * 64;

    for (int i = tid; i < 64 * 32; i += 256) {
        int r = i >> 5, c = (i & 31) * 4;
        fx4 v = {0.f, 0.f, 0.f, 0.f};
        int gr = row0 + r;
        if (gr < M) v = ld4(X + (size_t)gr * 128 + c);
        st4(&Xs[r * 132 + c], v);
    }
    __syncthreads();

    const int ty = tid >> 4, tx = tid & 15;
    fx4 acc[4][2];
    mm64f<0>(Xs, W, ty, tx, acc);
    #pragma unroll
    for (int r = 0; r < 4; ++r) {
        int gr = row0 + ty * 4 + r;
        if (gr < M) {
            st4(Out + (size_t)gr * 128 + tx * 8, acc[r][0]);
            st4(Out + (size_t)gr * 128 + tx * 8 + 4, acc[r][1]);
        }
    }
}

// ---------------- weight prep ------------------------------------------------
struct TJob { const float* src; unsigned short* dst; int K; };
struct TJobs { TJob j[16]; };

__global__ __launch_bounds__(256) void transpose_kernel(TJobs jobs) {
    TJob t = jobs.j[blockIdx.x];
    int total = 128 * t.K;
    for (int i = threadIdx.x; i < total; i += 256) {
        int n = i / t.K, k = i - n * t.K;
        t.dst[(size_t)n * t.K + k] = f2bf(t.src[(size_t)k * 128 + n]);
    }
}

// bep[l][n] = ml_b1[l][n] + sum_k ee_b2[k] * W1b_l[k][n]
__global__ __launch_bounds__(128) void bep_kernel(
    const float* __restrict__ ee_b2, const float* __restrict__ ml_w1,
    const float* __restrict__ ml_b1, float* __restrict__ bep)
{
    int l = blockIdx.x, n = threadIdx.x;
    const float* W1b = ml_w1 + (size_t)l * 384 * 128 + 128 * 128;
    float s = ml_b1[(size_t)l * 128 + n];
    for (int k = 0; k < 128; ++k) s += ee_b2[k] * W1b[(size_t)k * 128 + n];
    bep[(size_t)l * 128 + n] = s;
}

// ---------------- CSR build --------------------------------------------------
__global__ __launch_bounds__(256) void csr_hist_kernel(
    const int* __restrict__ el, int* __restrict__ cnt, int NE)
{
    int e = blockIdx.x * 256 + threadIdx.x;
    if (e < NE) {
        atomicAdd(&cnt[el[2 * (size_t)e + 1]], 1);
        atomicAdd(&cnt[el[2 * (size_t)e]], 1);
    }
}

__global__ __launch_bounds__(256) void csr_scan_kernel(
    const int* __restrict__ cnt, int* __restrict__ startp, int NN)
{
    __shared__ int part[256];
    const int t = threadIdx.x;
    const int chunk = (NN + 255) / 256;
    const int lo = t * chunk;
    const int hi = min(lo + chunk, NN);
    int s = 0;
    for (int i = lo; i < hi; ++i) s += cnt[i];
    part[t] = s;
    __syncthreads();
    for (int off = 1; off < 256; off <<= 1) {
        int u = (t >= off) ? part[t - off] : 0;
        __syncthreads();
        part[t] += u;
        __syncthreads();
    }
    int run = part[t] - s;
    for (int i = lo; i < hi; ++i) { startp[i] = run; run += cnt[i]; }
    if (t == 255) startp[NN] = part[255];
}

// inc[pos] = {other_endpoint, edge_id}
__global__ __launch_bounds__(256) void csr_fill_kernel(
    const int* __restrict__ el, const int* __restrict__ startp,
    int* __restrict__ cursor, int2* __restrict__ inc, int NE)
{
    int e = blockIdx.x * 256 + threadIdx.x;
    if (e < NE) {
        int s = el[2 * (size_t)e], d = el[2 * (size_t)e + 1];
        int p = startp[d] + atomicAdd(&cursor[d], 1);
        inc[p] = make_int2(s, e);        // msg into d, other = s
        int q = startp[s] + atomicAdd(&cursor[s], 1);
        inc[q] = make_int2(d, e);        // msg into s, other = d
    }
}

// ---------------- gather: S[n] = sum_j relu(P1[o_j] + Ep[e_j] + P3[n]) -------
// One wave per node; 16 lanes x 16B cover a 256B row; 4 lane-slots process
// 4 incidences of the same node concurrently; shfl-reduce across slots.
__global__ __launch_bounds__(256) void gather_kernel(
    const unsigned short* __restrict__ P1bf, const unsigned short* __restrict__ P3bf,
    const unsigned short* __restrict__ Ep, const int2* __restrict__ inc,
    const int* __restrict__ startp, unsigned short* __restrict__ S, int M)
{
    const int tid = threadIdx.x;
    const int lane = tid & 63;
    const int n = blockIdx.x * 4 + (tid >> 6);
    if (n >= M) return;
    const int slot = lane >> 4;
    const int c = (lane & 15) * 8;

    float p3[8], acc[8];
    us8 u3 = *reinterpret_cast<const us8*>(&P3bf[(size_t)n * 128 + c]);
    #pragma unroll
    for (int i = 0; i < 8; ++i) {
        p3[i] = bf2f((unsigned int)(unsigned short)u3[i]);
        acc[i] = 0.f;
    }

    const int j1 = startp[n + 1];
    int j = startp[n] + slot;
    int2 oe = (j < j1) ? inc[j] : make_int2(0, 0);
    while (j < j1) {
        int jn = j + 4;
        int2 oen = (jn < j1) ? inc[jn] : make_int2(0, 0);   // prefetch next
        us8 u1 = *reinterpret_cast<const us8*>(&P1bf[(size_t)oe.x * 128 + c]);
        us8 ue = *reinterpret_cast<const us8*>(&Ep[(size_t)oe.y * 128 + c]);
        #pragma unroll
        for (int i = 0; i < 8; ++i)
            acc[i] += fmaxf(p3[i] + bf2f((unsigned int)(unsigned short)u1[i])
                                  + bf2f((unsigned int)(unsigned short)ue[i]), 0.f);
        j = jn; oe = oen;
    }

    #pragma unroll
    for (int i = 0; i < 8; ++i) {
        acc[i] += __shfl_xor(acc[i], 16, 64);
        acc[i] += __shfl_xor(acc[i], 32, 64);
    }
    if (slot == 0) {
        us8 pk;
        #pragma unroll
        for (int i = 0; i < 8; ++i) pk[i] = f2bf(acc[i]);
        *reinterpret_cast<us8*>(&S[(size_t)n * 128 + c]) = pk;
    }
}

// ---------------- host launch ------------------------------------------------
extern "C" void kernel_launch(void* const* d_in, const int* in_sizes, int n_in,
                              void* d_out, int out_size, void* d_ws, size_t ws_size,
                              hipStream_t stream) {
    const float* node_f    = (const float*)d_in[0];
    const int*   edge_list = (const int*)d_in[1];
    const float* edge_f    = (const float*)d_in[2];
    const float* ne_w1 = (const float*)d_in[4];
    const float* ne_b1 = (const float*)d_in[5];
    const float* ne_w2 = (const float*)d_in[6];
    const float* ne_b2 = (const float*)d_in[7];
    const float* ee_w1 = (const float*)d_in[8];
    const float* ee_b1 = (const float*)d_in[9];
    const float* ee_w2 = (const float*)d_in[10];
    const float* ee_b2 = (const float*)d_in[11];
    const float* ml_w1 = (const float*)d_in[12];
    const float* ml_b1 = (const float*)d_in[13];
    const float* ml_w2 = (const float*)d_in[14];
    const float* ml_b2 = (const float*)d_in[15];
    const float* agg_w1 = (const float*)d_in[16];
    const float* agg_b1 = (const float*)d_in[17];
    const float* agg_w2 = (const float*)d_in[18];
    const float* agg_b2 = (const float*)d_in[19];

    const int NN = in_sizes[0] / 128;
    const int NE = in_sizes[1] / 2;
    const int n_layers = in_sizes[12] / (384 * 128);

    // ---- workspace layout (256B-aligned blocks) ----
    char* p = (char*)d_ws;
    auto alloc = [&](size_t bytes) -> void* {
        void* r = (void*)p;
        p += (bytes + 255) & ~(size_t)255;
        return r;
    };
    float* node_emb = (float*)alloc((size_t)NN * 128 * 4);
    unsigned short* P1bf = (unsigned short*)alloc((size_t)NN * 128 * 2);
    unsigned short* P3bf = (unsigned short*)alloc((size_t)NN * 128 * 2);
    unsigned short* bufS = (unsigned short*)alloc((size_t)NN * 128 * 2);
    unsigned short* H_edge = (unsigned short*)alloc((size_t)NE * 128 * 2);
    unsigned short* Ep = (unsigned short*)alloc((size_t)NE * 128 * 2);
    unsigned short* ne_w1t = (unsigned short*)alloc(128 * 128 * 2);
    unsigned short* ne_w2t = (unsigned short*)alloc(128 * 128 * 2);
    unsigned short* ee_w1t = (unsigned short*)alloc(128 * 64 * 2);
    unsigned short* aw1t = (unsigned short*)alloc(128 * 128 * 2);
    unsigned short* aw2t = (unsigned short*)alloc(128 * 128 * 2);
    unsigned short* W13t[2], *W2t[2], *Wept[2];
    float* Wepf[2];
    for (int l = 0; l < 2; ++l) {
        W13t[l] = (unsigned short*)alloc(256 * 128 * 2);   // [W1a^T ; W1c^T]
        W2t[l]  = (unsigned short*)alloc(128 * 128 * 2);
        Wept[l] = (unsigned short*)alloc(128 * 128 * 2);
        Wepf[l] = (float*)alloc(128 * 128 * 4);
    }
    float* bep = (float*)alloc((size_t)2 * 128 * 4);
    int* cnt = (int*)alloc((size_t)NN * 4);
    int* startp = (int*)alloc((size_t)(NN + 1) * 4);
    int2* inc = (int2*)alloc((size_t)2 * NE * 8);
    size_t need = (size_t)(p - (char*)d_ws);
    if (ws_size < need) return;

    dim3 blk(256);
    const int gM_N = (NN + 127) / 128;
    const int gM_E = (NE + 127) / 128;
    const int gE256 = (NE + 255) / 256;

    // ---- weight prep ----
    for (int l = 0; l < n_layers && l < 2; ++l) {
        const float* W1b = ml_w1 + (size_t)l * 384 * 128 + 128 * 128;
        gemm128_kernel<<<2, blk, 0, stream>>>(ee_w2, W1b, Wepf[l], 128);
    }
    {
        TJobs jobs{};
        int nj = 0;
        jobs.j[nj++] = {ne_w1, ne_w1t, 128};
        jobs.j[nj++] = {ne_w2, ne_w2t, 128};
        jobs.j[nj++] = {ee_w1, ee_w1t, 64};
        jobs.j[nj++] = {agg_w1, aw1t, 128};
        jobs.j[nj++] = {agg_w2, aw2t, 128};
        for (int l = 0; l < n_layers && l < 2; ++l) {
            jobs.j[nj++] = {ml_w1 + (size_t)l * 384 * 128, W13t[l], 128};
            jobs.j[nj++] = {ml_w1 + (size_t)l * 384 * 128 + 256 * 128, W13t[l] + 128 * 128, 128};
            jobs.j[nj++] = {ml_w2 + (size_t)l * 128 * 128, W2t[l], 128};
            jobs.j[nj++] = {Wepf[l], Wept[l], 128};
        }
        transpose_kernel<<<nj, blk, 0, stream>>>(jobs);
    }
    bep_kernel<<<n_layers, 128, 0, stream>>>(ee_b2, ml_w1, ml_b1, bep);

    // ---- encoders ----
    mfma_gemm<128, true, true, true, false, true, false><<<gM_N, blk, 0, stream>>>(
        node_f, ne_w1t, ne_b1, nullptr, bufS, nullptr, nullptr, NN);
    mfma_gemm<128, false, true, false, true, false, false><<<gM_N, blk, 0, stream>>>(
        bufS, ne_w2t, ne_b2, node_emb, nullptr, nullptr, nullptr, NN);
    mfma_gemm<64, true, true, true, false, true, false><<<gM_E, blk, 0, stream>>>(
        edge_f, ee_w1t, ee_b1, nullptr, H_edge, nullptr, nullptr, NE);

    // ---- CSR incidence ----
    hipMemsetAsync(cnt, 0, (size_t)NN * sizeof(int), stream);
    csr_hist_kernel<<<gE256, blk, 0, stream>>>(edge_list, cnt, NE);
    csr_scan_kernel<<<1, blk, 0, stream>>>(cnt, startp, NN);
    hipMemsetAsync(cnt, 0, (size_t)NN * sizeof(int), stream);
    csr_fill_kernel<<<gE256, blk, 0, stream>>>(edge_list, startp, cnt, inc, NE);

    float* out = (float*)d_out;
    for (int l = 0; l < n_layers && l < 2; ++l) {
        // [P1|P3] = node_emb @ [W1a|W1c]
        mfma_gemm_dual<<<gM_N, blk, 0, stream>>>(node_emb, W13t[l], P1bf, P3bf, NN);
        // Ep = H_edge @ Wep + bep
        mfma_gemm<128, false, true, false, false, true, false><<<gM_E, blk, 0, stream>>>(
            H_edge, Wept[l], bep + (size_t)l * 128, nullptr, Ep, nullptr, nullptr, NE);
        // S = gather-sum of relu'd hiddens -> bufS
        gather_kernel<<<(NN + 3) / 4, blk, 0, stream>>>(
            P1bf, P3bf, Ep, inc, startp, bufS, NN);
        // X = node_emb + S@W2 + deg*b2 -> P1bf (bf16)
        mfma_gemm<128, false, true, false, false, true, true><<<gM_N, blk, 0, stream>>>(
            bufS, W2t[l], ml_b2 + (size_t)l * 128, nullptr, P1bf, node_emb, startp, NN);
        // H1 = relu(X @ aw1 + ab1) -> bufS
        mfma_gemm<128, false, true, true, false, true, false><<<gM_N, blk, 0, stream>>>(
            P1bf, aw1t, agg_b1, nullptr, bufS, nullptr, nullptr, NN);
        // out = H1 @ aw2 + ab2
        float* dst = (l == n_layers - 1) ? out : node_emb;
        mfma_gemm<128, false, true, false, true, false, false><<<gM_N, blk, 0, stream>>>(
            bufS, aw2t, agg_b2, dst, nullptr, nullptr, nullptr, NN);
    }
}

// Round 5
// 625.056 us; speedup vs baseline: 10.6359x; 1.1790x over previous
//
#include <hip/hip_runtime.h>

typedef float fx4 __attribute__((ext_vector_type(4)));
typedef float f32x4 __attribute__((ext_vector_type(4)));
typedef unsigned short us8 __attribute__((ext_vector_type(8)));
typedef __bf16 bf8 __attribute__((ext_vector_type(8)));

static __device__ __forceinline__ fx4 ld4(const float* p) {
    return *reinterpret_cast<const fx4*>(p);
}
static __device__ __forceinline__ void st4(float* p, fx4 v) {
    *reinterpret_cast<fx4*>(p) = v;
}
static __device__ __forceinline__ unsigned short f2bf(float f) {
    union { float f; unsigned int i; } x; x.f = f;
    unsigned int r = x.i + 0x7FFF + ((x.i >> 16) & 1);   // RNE
    return (unsigned short)(r >> 16);
}
static __device__ __forceinline__ float bf2f(unsigned int u) {
    union { unsigned int i; float f; } x; x.i = u << 16; return x.f;
}

static __device__ __forceinline__ f32x4 mfma16(us8 a, us8 b, f32x4 c) {
    return __builtin_amdgcn_mfma_f32_16x16x32_bf16(
        __builtin_bit_cast(bf8, a), __builtin_bit_cast(bf8, b), c, 0, 0, 0);
}

// ---------------- MFMA GEMM: Out[M][128] = A[M][K1] @ W[K1][128] (+epilogue) ---
// Wt is transposed bf16 weight: Wt[n][k] = W[k][n].
// XMODE: out = acc + resid[r][col] + deg[r]*bias[col]  (no plain bias, no relu)
template <int K1, bool AF32, bool BIAS, bool RELU, bool OUTF, bool OUTB, bool XMODE>
__global__ __launch_bounds__(256) void mfma_gemm(
    const void* __restrict__ Av, const unsigned short* __restrict__ Wt,
    const float* __restrict__ bias,
    float* __restrict__ outF, unsigned short* __restrict__ outB,
    const float* __restrict__ resid, const int* __restrict__ startp, int M)
{
    constexpr int KP = K1 + 8;                     // padded LDS row, bf16 units
    __shared__ unsigned short Ws[128 * KP];
    const int tid = threadIdx.x;
    const int lane = tid & 63;
    const int wv = tid >> 6;
    const int row0 = blockIdx.x * 128 + wv * 32;

    constexpr int C8 = K1 / 8;
    for (int i = tid; i < 128 * C8; i += 256) {
        int r = i / C8, c = (i % C8) * 8;
        *reinterpret_cast<us8*>(&Ws[r * KP + c]) =
            *reinterpret_cast<const us8*>(&Wt[r * K1 + c]);
    }
    __syncthreads();

    const int ar = lane & 15;            // A row / B col within 16-tile
    const int ak = (lane >> 4) * 8;      // k offset within 32-k step

    f32x4 acc[2][8];
    #pragma unroll
    for (int m = 0; m < 2; ++m)
        #pragma unroll
        for (int nt = 0; nt < 8; ++nt) acc[m][nt] = {0.f, 0.f, 0.f, 0.f};

    #pragma unroll
    for (int kk = 0; kk < K1 / 32; ++kk) {
        us8 a[2];
        #pragma unroll
        for (int m = 0; m < 2; ++m) {
            int row = row0 + m * 16 + ar;
            us8 t = 0;
            if (row < M) {
                if (AF32) {
                    const float* ap = (const float*)Av + (size_t)row * K1 + kk * 32 + ak;
                    fx4 x0 = ld4(ap), x1 = ld4(ap + 4);
                    #pragma unroll
                    for (int j = 0; j < 4; ++j) {
                        t[j] = f2bf(x0[j]);
                        t[4 + j] = f2bf(x1[j]);
                    }
                } else {
                    t = *reinterpret_cast<const us8*>(
                        (const unsigned short*)Av + (size_t)row * K1 + kk * 32 + ak);
                }
            }
            a[m] = t;
        }
        #pragma unroll
        for (int nt = 0; nt < 8; ++nt) {
            us8 b = *reinterpret_cast<const us8*>(&Ws[(nt * 16 + ar) * KP + kk * 32 + ak]);
            acc[0][nt] = mfma16(a[0], b, acc[0][nt]);
            acc[1][nt] = mfma16(a[1], b, acc[1][nt]);
        }
    }

    const int crow = (lane >> 4) * 4;
    const int ccol = lane & 15;
    #pragma unroll
    for (int m = 0; m < 2; ++m) {
        int rbase = row0 + m * 16 + crow;
        float deg[4];
        if (XMODE) {
            #pragma unroll
            for (int i = 0; i < 4; ++i) {
                int r = rbase + i;
                deg[i] = (r < M) ? (float)(startp[r + 1] - startp[r]) : 0.f;
            }
        }
        #pragma unroll
        for (int nt = 0; nt < 8; ++nt) {
            int col = nt * 16 + ccol;
            float bc = BIAS ? bias[col] : 0.f;
            #pragma unroll
            for (int i = 0; i < 4; ++i) {
                int r = rbase + i;
                if (r >= M) continue;
                float o = acc[m][nt][i];
                if (XMODE) o += resid[(size_t)r * 128 + col] + deg[i] * bc;
                else if (BIAS) o += bc;
                if (RELU) o = fmaxf(o, 0.f);
                if (OUTF) outF[(size_t)r * 128 + col] = o;
                if (OUTB) outB[(size_t)r * 128 + col] = f2bf(o);
            }
        }
    }
}

// ---- fused 2-layer MLP: out = relu(A@W1+b1)@W2 + b2 -------------------------
// K1 = 128 only. Hidden stays on-chip: per-wave LDS transpose reusing Ws1.
template <bool AF32, bool OUTF, bool OUTB>
__global__ __launch_bounds__(256) void mfma_mlp(
    const void* __restrict__ Av, const unsigned short* __restrict__ W1t,
    const float* __restrict__ b1, const unsigned short* __restrict__ W2t,
    const float* __restrict__ b2,
    float* __restrict__ outF, unsigned short* __restrict__ outB, int M)
{
    constexpr int KP = 136;
    __shared__ unsigned short Ws1[128 * KP];   // W1, later reused as H tile
    __shared__ unsigned short Ws2[128 * KP];
    const int tid = threadIdx.x;
    const int lane = tid & 63;
    const int wv = tid >> 6;
    const int row0 = blockIdx.x * 128 + wv * 32;

    for (int i = tid; i < 128 * 16; i += 256) {
        int r = i >> 4, c = (i & 15) * 8;
        *reinterpret_cast<us8*>(&Ws1[r * KP + c]) =
            *reinterpret_cast<const us8*>(&W1t[r * 128 + c]);
        *reinterpret_cast<us8*>(&Ws2[r * KP + c]) =
            *reinterpret_cast<const us8*>(&W2t[r * 128 + c]);
    }
    __syncthreads();

    const int ar = lane & 15;
    const int ak = (lane >> 4) * 8;
    const int crow = (lane >> 4) * 4;
    const int ccol = lane & 15;

    // phase 1: H = relu(A@W1 + b1)
    f32x4 acc[2][8];
    #pragma unroll
    for (int m = 0; m < 2; ++m)
        #pragma unroll
        for (int nt = 0; nt < 8; ++nt) acc[m][nt] = {0.f, 0.f, 0.f, 0.f};

    #pragma unroll
    for (int kk = 0; kk < 4; ++kk) {
        us8 a[2];
        #pragma unroll
        for (int m = 0; m < 2; ++m) {
            int row = row0 + m * 16 + ar;
            us8 t = 0;
            if (row < M) {
                if (AF32) {
                    const float* ap = (const float*)Av + (size_t)row * 128 + kk * 32 + ak;
                    fx4 x0 = ld4(ap), x1 = ld4(ap + 4);
                    #pragma unroll
                    for (int j = 0; j < 4; ++j) {
                        t[j] = f2bf(x0[j]);
                        t[4 + j] = f2bf(x1[j]);
                    }
                } else {
                    t = *reinterpret_cast<const us8*>(
                        (const unsigned short*)Av + (size_t)row * 128 + kk * 32 + ak);
                }
            }
            a[m] = t;
        }
        #pragma unroll
        for (int nt = 0; nt < 8; ++nt) {
            us8 b = *reinterpret_cast<const us8*>(&Ws1[(nt * 16 + ar) * KP + kk * 32 + ak]);
            acc[0][nt] = mfma16(a[0], b, acc[0][nt]);
            acc[1][nt] = mfma16(a[1], b, acc[1][nt]);
        }
    }
    __syncthreads();    // all waves done reading W1 before overwrite

    // write H (bf16) into Ws1, local rows wv*32 .. +32
    #pragma unroll
    for (int m = 0; m < 2; ++m) {
        int lbase = wv * 32 + m * 16 + crow;
        #pragma unroll
        for (int nt = 0; nt < 8; ++nt) {
            int col = nt * 16 + ccol;
            float bc = b1[col];
            #pragma unroll
            for (int i = 0; i < 4; ++i)
                Ws1[(lbase + i) * KP + col] = f2bf(fmaxf(acc[m][nt][i] + bc, 0.f));
        }
    }
    __syncthreads();

    // phase 2: out = H @ W2 + b2
    f32x4 acc2[2][8];
    #pragma unroll
    for (int m = 0; m < 2; ++m)
        #pragma unroll
        for (int nt = 0; nt < 8; ++nt) acc2[m][nt] = {0.f, 0.f, 0.f, 0.f};

    #pragma unroll
    for (int kk = 0; kk < 4; ++kk) {
        us8 a[2];
        #pragma unroll
        for (int m = 0; m < 2; ++m) {
            int lrow = wv * 32 + m * 16 + ar;
            a[m] = *reinterpret_cast<const us8*>(&Ws1[lrow * KP + kk * 32 + ak]);
        }
        #pragma unroll
        for (int nt = 0; nt < 8; ++nt) {
            us8 b = *reinterpret_cast<const us8*>(&Ws2[(nt * 16 + ar) * KP + kk * 32 + ak]);
            acc2[0][nt] = mfma16(a[0], b, acc2[0][nt]);
            acc2[1][nt] = mfma16(a[1], b, acc2[1][nt]);
        }
    }

    #pragma unroll
    for (int m = 0; m < 2; ++m) {
        int rbase = row0 + m * 16 + crow;
        #pragma unroll
        for (int nt = 0; nt < 8; ++nt) {
            int col = nt * 16 + ccol;
            float bc = b2[col];
            #pragma unroll
            for (int i = 0; i < 4; ++i) {
                int r = rbase + i;
                if (r >= M) continue;
                float o = acc2[m][nt][i] + bc;
                if (OUTF) outF[(size_t)r * 128 + col] = o;
                if (OUTB) outB[(size_t)r * 128 + col] = f2bf(o);
            }
        }
    }
}

// ---- dual-output GEMM: [P1|P3] = A[M][128] @ [W1a|W1c]; Wt is 256 rows x 128k
__global__ __launch_bounds__(256) void mfma_gemm_dual(
    const float* __restrict__ A, const unsigned short* __restrict__ Wt,
    unsigned short* __restrict__ out1, unsigned short* __restrict__ out2, int M)
{
    constexpr int KP = 136;
    __shared__ unsigned short Ws[256 * KP];
    const int tid = threadIdx.x;
    const int lane = tid & 63;
    const int wv = tid >> 6;
    const int row0 = blockIdx.x * 128 + wv * 32;

    for (int i = tid; i < 256 * 16; i += 256) {
        int r = i >> 4, c = (i & 15) * 8;
        *reinterpret_cast<us8*>(&Ws[r * KP + c]) =
            *reinterpret_cast<const us8*>(&Wt[r * 128 + c]);
    }
    __syncthreads();

    const int ar = lane & 15;
    const int ak = (lane >> 4) * 8;

    f32x4 acc[2][16];
    #pragma unroll
    for (int m = 0; m < 2; ++m)
        #pragma unroll
        for (int nt = 0; nt < 16; ++nt) acc[m][nt] = {0.f, 0.f, 0.f, 0.f};

    #pragma unroll
    for (int kk = 0; kk < 4; ++kk) {
        us8 a[2];
        #pragma unroll
        for (int m = 0; m < 2; ++m) {
            int row = row0 + m * 16 + ar;
            us8 t = 0;
            if (row < M) {
                const float* ap = A + (size_t)row * 128 + kk * 32 + ak;
                fx4 x0 = ld4(ap), x1 = ld4(ap + 4);
                #pragma unroll
                for (int j = 0; j < 4; ++j) {
                    t[j] = f2bf(x0[j]);
                    t[4 + j] = f2bf(x1[j]);
                }
            }
            a[m] = t;
        }
        #pragma unroll
        for (int nt = 0; nt < 16; ++nt) {
            us8 b = *reinterpret_cast<const us8*>(&Ws[(nt * 16 + ar) * KP + kk * 32 + ak]);
            acc[0][nt] = mfma16(a[0], b, acc[0][nt]);
            acc[1][nt] = mfma16(a[1], b, acc[1][nt]);
        }
    }

    const int crow = (lane >> 4) * 4;
    const int ccol = lane & 15;
    #pragma unroll
    for (int m = 0; m < 2; ++m) {
        int rbase = row0 + m * 16 + crow;
        #pragma unroll
        for (int nt = 0; nt < 16; ++nt) {
            int col = nt * 16 + ccol;
            unsigned short* o = (nt < 8) ? out1 : out2;
            int oc = col & 127;
            #pragma unroll
            for (int i = 0; i < 4; ++i) {
                int r = rbase + i;
                if (r >= M) continue;
                o[(size_t)r * 128 + oc] = f2bf(acc[m][nt][i]);
            }
        }
    }
}

// ---------------- fp32 helper GEMM for the tiny weight-fold (M=128) ----------
template <int DUMMY>
static __device__ __forceinline__ void mm64f(const float* A, const float* __restrict__ W,
                                             int ty, int tx, fx4 acc[4][2]) {
    #pragma unroll
    for (int r = 0; r < 4; ++r) { acc[r][0] = 0.f; acc[r][1] = 0.f; }
    for (int k = 0; k < 128; k += 4) {
        fx4 xr[4];
        #pragma unroll
        for (int r = 0; r < 4; ++r) xr[r] = ld4(A + (ty * 4 + r) * 132 + k);
        #pragma unroll
        for (int kk = 0; kk < 4; ++kk) {
            fx4 wa = ld4(W + (size_t)(k + kk) * 128 + tx * 8);
            fx4 wb = ld4(W + (size_t)(k + kk) * 128 + tx * 8 + 4);
            #pragma unroll
            for (int r = 0; r < 4; ++r) {
                acc[r][0] += xr[r][kk] * wa;
                acc[r][1] += xr[r][kk] * wb;
            }
        }
    }
}

__global__ __launch_bounds__(256) void gemm128_kernel(
    const float* __restrict__ X, const float* __restrict__ W,
    float* __restrict__ Out, int M)
{
    __shared__ float Xs[64 * 132];
    const int tid = threadIdx.x;
    const int row0 = blockIdx.x * 64;

    for (int i = tid; i < 64 * 32; i += 256) {
        int r = i >> 5, c = (i & 31) * 4;
        fx4 v = {0.f, 0.f, 0.f, 0.f};
        int gr = row0 + r;
        if (gr < M) v = ld4(X + (size_t)gr * 128 + c);
        st4(&Xs[r * 132 + c], v);
    }
    __syncthreads();

    const int ty = tid >> 4, tx = tid & 15;
    fx4 acc[4][2];
    mm64f<0>(Xs, W, ty, tx, acc);
    #pragma unroll
    for (int r = 0; r < 4; ++r) {
        int gr = row0 + ty * 4 + r;
        if (gr < M) {
            st4(Out + (size_t)gr * 128 + tx * 8, acc[r][0]);
            st4(Out + (size_t)gr * 128 + tx * 8 + 4, acc[r][1]);
        }
    }
}

// ---------------- weight prep ------------------------------------------------
struct TJob { const float* src; unsigned short* dst; int K; };
struct TJobs { TJob j[16]; };

__global__ __launch_bounds__(256) void transpose_kernel(TJobs jobs) {
    TJob t = jobs.j[blockIdx.x];
    int total = 128 * t.K;
    for (int i = threadIdx.x; i < total; i += 256) {
        int n = i / t.K, k = i - n * t.K;
        t.dst[(size_t)n * t.K + k] = f2bf(t.src[(size_t)k * 128 + n]);
    }
}

// bep[l][n] = ml_b1[l][n] + sum_k ee_b2[k] * W1b_l[k][n]
__global__ __launch_bounds__(128) void bep_kernel(
    const float* __restrict__ ee_b2, const float* __restrict__ ml_w1,
    const float* __restrict__ ml_b1, float* __restrict__ bep)
{
    int l = blockIdx.x, n = threadIdx.x;
    const float* W1b = ml_w1 + (size_t)l * 384 * 128 + 128 * 128;
    float s = ml_b1[(size_t)l * 128 + n];
    for (int k = 0; k < 128; ++k) s += ee_b2[k] * W1b[(size_t)k * 128 + n];
    bep[(size_t)l * 128 + n] = s;
}

// ---------------- CSR build --------------------------------------------------
__global__ __launch_bounds__(256) void csr_hist_kernel(
    const int* __restrict__ el, int* __restrict__ cnt, int NE)
{
    int e = blockIdx.x * 256 + threadIdx.x;
    if (e < NE) {
        atomicAdd(&cnt[el[2 * (size_t)e + 1]], 1);
        atomicAdd(&cnt[el[2 * (size_t)e]], 1);
    }
}

// pass 1: per-block sums (256 elements per block)
__global__ __launch_bounds__(256) void scan_p1_kernel(
    const int* __restrict__ cnt, int* __restrict__ bsum, int NN)
{
    __shared__ int red[256];
    const int t = threadIdx.x;
    int i = blockIdx.x * 256 + t;
    red[t] = (i < NN) ? cnt[i] : 0;
    __syncthreads();
    for (int off = 128; off > 0; off >>= 1) {
        if (t < off) red[t] += red[t + off];
        __syncthreads();
    }
    if (t == 0) bsum[blockIdx.x] = red[0];
}

// pass 2: exclusive scan of <=256 block sums; also writes startp[NN] = total
__global__ __launch_bounds__(256) void scan_p2_kernel(
    int* __restrict__ bsum, int* __restrict__ startp, int nb, int NN)
{
    __shared__ int part[256];
    const int t = threadIdx.x;
    int v = (t < nb) ? bsum[t] : 0;
    part[t] = v;
    __syncthreads();
    for (int off = 1; off < 256; off <<= 1) {
        int u = (t >= off) ? part[t - off] : 0;
        __syncthreads();
        part[t] += u;
        __syncthreads();
    }
    if (t < nb) bsum[t] = part[t] - v;     // exclusive block offset
    if (t == 255) startp[NN] = part[255];  // total
}

// pass 3: local exclusive scan + block offset; zeroes cnt (cursor prep)
__global__ __launch_bounds__(256) void scan_p3_kernel(
    int* __restrict__ cnt, const int* __restrict__ bsum,
    int* __restrict__ startp, int NN)
{
    __shared__ int part[256];
    const int t = threadIdx.x;
    int i = blockIdx.x * 256 + t;
    int v = (i < NN) ? cnt[i] : 0;
    part[t] = v;
    __syncthreads();
    for (int off = 1; off < 256; off <<= 1) {
        int u = (t >= off) ? part[t - off] : 0;
        __syncthreads();
        part[t] += u;
        __syncthreads();
    }
    if (i < NN) {
        startp[i] = bsum[blockIdx.x] + part[t] - v;
        cnt[i] = 0;
    }
}

// inc[pos] = {other_endpoint, edge_id}
__global__ __launch_bounds__(256) void csr_fill_kernel(
    const int* __restrict__ el, const int* __restrict__ startp,
    int* __restrict__ cursor, int2* __restrict__ inc, int NE)
{
    int e = blockIdx.x * 256 + threadIdx.x;
    if (e < NE) {
        int s = el[2 * (size_t)e], d = el[2 * (size_t)e + 1];
        int p = startp[d] + atomicAdd(&cursor[d], 1);
        inc[p] = make_int2(s, e);        // msg into d, other = s
        int q = startp[s] + atomicAdd(&cursor[s], 1);
        inc[q] = make_int2(d, e);        // msg into s, other = d
    }
}

// ---------------- gather: S[n] = sum_j relu(P1[o_j] + Ep[e_j] + P3[n]) -------
__global__ __launch_bounds__(256) void gather_kernel(
    const unsigned short* __restrict__ P1bf, const unsigned short* __restrict__ P3bf,
    const unsigned short* __restrict__ Ep, const int2* __restrict__ inc,
    const int* __restrict__ startp, unsigned short* __restrict__ S, int M)
{
    const int tid = threadIdx.x;
    const int lane = tid & 63;
    const int n = blockIdx.x * 4 + (tid >> 6);
    if (n >= M) return;
    const int slot = lane >> 4;
    const int c = (lane & 15) * 8;

    float p3[8], acc[8];
    us8 u3 = *reinterpret_cast<const us8*>(&P3bf[(size_t)n * 128 + c]);
    #pragma unroll
    for (int i = 0; i < 8; ++i) {
        p3[i] = bf2f((unsigned int)(unsigned short)u3[i]);
        acc[i] = 0.f;
    }

    const int j1 = startp[n + 1];
    int j = startp[n] + slot;
    int2 oe = (j < j1) ? inc[j] : make_int2(0, 0);
    while (j < j1) {
        int jn = j + 4;
        int2 oen = (jn < j1) ? inc[jn] : make_int2(0, 0);   // prefetch next
        us8 u1 = *reinterpret_cast<const us8*>(&P1bf[(size_t)oe.x * 128 + c]);
        us8 ue = *reinterpret_cast<const us8*>(&Ep[(size_t)oe.y * 128 + c]);
        #pragma unroll
        for (int i = 0; i < 8; ++i)
            acc[i] += fmaxf(p3[i] + bf2f((unsigned int)(unsigned short)u1[i])
                                  + bf2f((unsigned int)(unsigned short)ue[i]), 0.f);
        j = jn; oe = oen;
    }

    #pragma unroll
    for (int i = 0; i < 8; ++i) {
        acc[i] += __shfl_xor(acc[i], 16, 64);
        acc[i] += __shfl_xor(acc[i], 32, 64);
    }
    if (slot == 0) {
        us8 pk;
        #pragma unroll
        for (int i = 0; i < 8; ++i) pk[i] = f2bf(acc[i]);
        *reinterpret_cast<us8*>(&S[(size_t)n * 128 + c]) = pk;
    }
}

// ---------------- host launch ------------------------------------------------
extern "C" void kernel_launch(void* const* d_in, const int* in_sizes, int n_in,
                              void* d_out, int out_size, void* d_ws, size_t ws_size,
                              hipStream_t stream) {
    const float* node_f    = (const float*)d_in[0];
    const int*   edge_list = (const int*)d_in[1];
    const float* edge_f    = (const float*)d_in[2];
    const float* ne_w1 = (const float*)d_in[4];
    const float* ne_b1 = (const float*)d_in[5];
    const float* ne_w2 = (const float*)d_in[6];
    const float* ne_b2 = (const float*)d_in[7];
    const float* ee_w1 = (const float*)d_in[8];
    const float* ee_b1 = (const float*)d_in[9];
    const float* ee_w2 = (const float*)d_in[10];
    const float* ee_b2 = (const float*)d_in[11];
    const float* ml_w1 = (const float*)d_in[12];
    const float* ml_b1 = (const float*)d_in[13];
    const float* ml_w2 = (const float*)d_in[14];
    const float* ml_b2 = (const float*)d_in[15];
    const float* agg_w1 = (const float*)d_in[16];
    const float* agg_b1 = (const float*)d_in[17];
    const float* agg_w2 = (const float*)d_in[18];
    const float* agg_b2 = (const float*)d_in[19];

    const int NN = in_sizes[0] / 128;
    const int NE = in_sizes[1] / 2;
    const int n_layers = in_sizes[12] / (384 * 128);

    // ---- workspace layout (256B-aligned blocks) ----
    char* p = (char*)d_ws;
    auto alloc = [&](size_t bytes) -> void* {
        void* r = (void*)p;
        p += (bytes + 255) & ~(size_t)255;
        return r;
    };
    float* node_emb = (float*)alloc((size_t)NN * 128 * 4);
    unsigned short* P1bf = (unsigned short*)alloc((size_t)NN * 128 * 2);
    unsigned short* P3bf = (unsigned short*)alloc((size_t)NN * 128 * 2);
    unsigned short* bufS = (unsigned short*)alloc((size_t)NN * 128 * 2);
    unsigned short* H_edge = (unsigned short*)alloc((size_t)NE * 128 * 2);
    unsigned short* Ep = (unsigned short*)alloc((size_t)NE * 128 * 2);
    unsigned short* ne_w1t = (unsigned short*)alloc(128 * 128 * 2);
    unsigned short* ne_w2t = (unsigned short*)alloc(128 * 128 * 2);
    unsigned short* ee_w1t = (unsigned short*)alloc(128 * 64 * 2);
    unsigned short* aw1t = (unsigned short*)alloc(128 * 128 * 2);
    unsigned short* aw2t = (unsigned short*)alloc(128 * 128 * 2);
    unsigned short* W13t[2], *W2t[2], *Wept[2];
    float* Wepf[2];
    for (int l = 0; l < 2; ++l) {
        W13t[l] = (unsigned short*)alloc(256 * 128 * 2);   // [W1a^T ; W1c^T]
        W2t[l]  = (unsigned short*)alloc(128 * 128 * 2);
        Wept[l] = (unsigned short*)alloc(128 * 128 * 2);
        Wepf[l] = (float*)alloc(128 * 128 * 4);
    }
    float* bep = (float*)alloc((size_t)2 * 128 * 4);
    int* cnt = (int*)alloc((size_t)NN * 4);
    int* startp = (int*)alloc((size_t)(NN + 1) * 4);
    int* bsum = (int*)alloc(256 * 4);
    int2* inc = (int2*)alloc((size_t)2 * NE * 8);
    size_t need = (size_t)(p - (char*)d_ws);
    if (ws_size < need) return;

    dim3 blk(256);
    const int gM_N = (NN + 127) / 128;
    const int gM_E = (NE + 127) / 128;
    const int gE256 = (NE + 255) / 256;
    const int nbScan = (NN + 255) / 256;   // must be <= 256

    // ---- weight prep ----
    for (int l = 0; l < n_layers && l < 2; ++l) {
        const float* W1b = ml_w1 + (size_t)l * 384 * 128 + 128 * 128;
        gemm128_kernel<<<2, blk, 0, stream>>>(ee_w2, W1b, Wepf[l], 128);
    }
    {
        TJobs jobs{};
        int nj = 0;
        jobs.j[nj++] = {ne_w1, ne_w1t, 128};
        jobs.j[nj++] = {ne_w2, ne_w2t, 128};
        jobs.j[nj++] = {ee_w1, ee_w1t, 64};
        jobs.j[nj++] = {agg_w1, aw1t, 128};
        jobs.j[nj++] = {agg_w2, aw2t, 128};
        for (int l = 0; l < n_layers && l < 2; ++l) {
            jobs.j[nj++] = {ml_w1 + (size_t)l * 384 * 128, W13t[l], 128};
            jobs.j[nj++] = {ml_w1 + (size_t)l * 384 * 128 + 256 * 128, W13t[l] + 128 * 128, 128};
            jobs.j[nj++] = {ml_w2 + (size_t)l * 128 * 128, W2t[l], 128};
            jobs.j[nj++] = {Wepf[l], Wept[l], 128};
        }
        transpose_kernel<<<nj, blk, 0, stream>>>(jobs);
    }
    bep_kernel<<<n_layers, 128, 0, stream>>>(ee_b2, ml_w1, ml_b1, bep);

    // ---- encoders ----
    // node_emb = mlp(node_f; ne_w1,ne_b1,ne_w2,ne_b2)  (fused pair)
    mfma_mlp<true, true, false><<<gM_N, blk, 0, stream>>>(
        node_f, ne_w1t, ne_b1, ne_w2t, ne_b2, node_emb, nullptr, NN);
    // H_edge = relu(edge_f @ ee_w1 + ee_b1) -> bf16
    mfma_gemm<64, true, true, true, false, true, false><<<gM_E, blk, 0, stream>>>(
        edge_f, ee_w1t, ee_b1, nullptr, H_edge, nullptr, nullptr, NE);

    // ---- CSR incidence ----
    hipMemsetAsync(cnt, 0, (size_t)NN * sizeof(int), stream);
    csr_hist_kernel<<<gE256, blk, 0, stream>>>(edge_list, cnt, NE);
    scan_p1_kernel<<<nbScan, blk, 0, stream>>>(cnt, bsum, NN);
    scan_p2_kernel<<<1, blk, 0, stream>>>(bsum, startp, nbScan, NN);
    scan_p3_kernel<<<nbScan, blk, 0, stream>>>(cnt, bsum, startp, NN);
    csr_fill_kernel<<<gE256, blk, 0, stream>>>(edge_list, startp, cnt, inc, NE);

    float* out = (float*)d_out;
    for (int l = 0; l < n_layers && l < 2; ++l) {
        // [P1|P3] = node_emb @ [W1a|W1c]
        mfma_gemm_dual<<<gM_N, blk, 0, stream>>>(node_emb, W13t[l], P1bf, P3bf, NN);
        // Ep = H_edge @ Wep + bep
        mfma_gemm<128, false, true, false, false, true, false><<<gM_E, blk, 0, stream>>>(
            H_edge, Wept[l], bep + (size_t)l * 128, nullptr, Ep, nullptr, nullptr, NE);
        // S = gather-sum of relu'd hiddens -> bufS
        gather_kernel<<<(NN + 3) / 4, blk, 0, stream>>>(
            P1bf, P3bf, Ep, inc, startp, bufS, NN);
        // X = node_emb + S@W2 + deg*b2 -> P1bf (bf16)
        mfma_gemm<128, false, true, false, false, true, true><<<gM_N, blk, 0, stream>>>(
            bufS, W2t[l], ml_b2 + (size_t)l * 128, nullptr, P1bf, node_emb, startp, NN);
        // out = mlp(X; aw1,ab1,aw2,ab2)  (fused pair)
        float* dst = (l == n_layers - 1) ? out : node_emb;
        mfma_mlp<false, true, false><<<gM_N, blk, 0, stream>>>(
            P1bf, aw1t, agg_b1, aw2t, agg_b2, dst, nullptr, NN);
    }
}

// Round 6
// 588.039 us; speedup vs baseline: 11.3055x; 1.0630x over previous
//
#include <hip/hip_runtime.h>

typedef float fx4 __attribute__((ext_vector_type(4)));
typedef float f32x4 __attribute__((ext_vector_type(4)));
typedef unsigned short us4v __attribute__((ext_vector_type(4)));
typedef unsigned short us8 __attribute__((ext_vector_type(8)));
typedef __bf16 bf8 __attribute__((ext_vector_type(8)));

static __device__ __forceinline__ fx4 ld4(const float* p) {
    return *reinterpret_cast<const fx4*>(p);
}
static __device__ __forceinline__ void st4(float* p, fx4 v) {
    *reinterpret_cast<fx4*>(p) = v;
}
static __device__ __forceinline__ unsigned short f2bf(float f) {
    union { float f; unsigned int i; } x; x.f = f;
    unsigned int r = x.i + 0x7FFF + ((x.i >> 16) & 1);   // RNE
    return (unsigned short)(r >> 16);
}
static __device__ __forceinline__ float bf2f(unsigned int u) {
    union { unsigned int i; float f; } x; x.i = u << 16; return x.f;
}
static __device__ __forceinline__ us4v pk4(f32x4 v) {
    us4v u;
    #pragma unroll
    for (int j = 0; j < 4; ++j) u[j] = f2bf(v[j]);
    return u;
}

// Swapped-operand MFMA: pass W-fragment first, Act-fragment second.
// D = W^T-tile * Act^T-tile  ==> lane holds 4 CONSECUTIVE OUTPUT COLS of one row:
//   out_row(within 16-blk) = lane&15, out_col_quad = (lane>>4)*4 + i
static __device__ __forceinline__ f32x4 mfma16(us8 a, us8 b, f32x4 c) {
    return __builtin_amdgcn_mfma_f32_16x16x32_bf16(
        __builtin_bit_cast(bf8, a), __builtin_bit_cast(bf8, b), c, 0, 0, 0);
}

// ---------------- MFMA GEMM: Out[M][128] = A[M][K1] @ W[K1][128] (+epilogue) ---
// Wt is transposed bf16 weight: Wt[n][k] = W[k][n].
// XMODE: out = acc + resid[r][col] + deg[r]*bias[col]
template <int K1, bool AF32, bool BIAS, bool RELU, bool OUTF, bool OUTB, bool XMODE>
__global__ __launch_bounds__(256) void mfma_gemm(
    const void* __restrict__ Av, const unsigned short* __restrict__ Wt,
    const float* __restrict__ bias,
    float* __restrict__ outF, unsigned short* __restrict__ outB,
    const float* __restrict__ resid, const int* __restrict__ startp, int M)
{
    constexpr int KP = K1 + 8;
    __shared__ unsigned short Ws[128 * KP];
    const int tid = threadIdx.x;
    const int lane = tid & 63;
    const int wv = tid >> 6;
    const int row0 = blockIdx.x * 128 + wv * 32;

    constexpr int C8 = K1 / 8;
    for (int i = tid; i < 128 * C8; i += 256) {
        int r = i / C8, c = (i % C8) * 8;
        *reinterpret_cast<us8*>(&Ws[r * KP + c]) =
            *reinterpret_cast<const us8*>(&Wt[r * K1 + c]);
    }
    __syncthreads();

    const int ar = lane & 15;
    const int ak = (lane >> 4) * 8;

    f32x4 acc[2][8];
    #pragma unroll
    for (int m = 0; m < 2; ++m)
        #pragma unroll
        for (int nt = 0; nt < 8; ++nt) acc[m][nt] = {0.f, 0.f, 0.f, 0.f};

    #pragma unroll
    for (int kk = 0; kk < K1 / 32; ++kk) {
        us8 a[2];
        #pragma unroll
        for (int m = 0; m < 2; ++m) {
            int row = row0 + m * 16 + ar;
            us8 t = 0;
            if (row < M) {
                if (AF32) {
                    const float* ap = (const float*)Av + (size_t)row * K1 + kk * 32 + ak;
                    fx4 x0 = ld4(ap), x1 = ld4(ap + 4);
                    #pragma unroll
                    for (int j = 0; j < 4; ++j) {
                        t[j] = f2bf(x0[j]);
                        t[4 + j] = f2bf(x1[j]);
                    }
                } else {
                    t = *reinterpret_cast<const us8*>(
                        (const unsigned short*)Av + (size_t)row * K1 + kk * 32 + ak);
                }
            }
            a[m] = t;
        }
        #pragma unroll
        for (int nt = 0; nt < 8; ++nt) {
            us8 b = *reinterpret_cast<const us8*>(&Ws[(nt * 16 + ar) * KP + kk * 32 + ak]);
            acc[0][nt] = mfma16(b, a[0], acc[0][nt]);   // swapped
            acc[1][nt] = mfma16(b, a[1], acc[1][nt]);
        }
    }

    // swapped epilogue: lane owns row (lane&15 within blk), col quad q*4
    const int q = lane >> 4;
    #pragma unroll
    for (int m = 0; m < 2; ++m) {
        int r = row0 + m * 16 + (lane & 15);
        if (r >= M) continue;
        float deg = 0.f;
        if (XMODE) deg = (float)(startp[r + 1] - startp[r]);
        #pragma unroll
        for (int nt = 0; nt < 8; ++nt) {
            int c0 = nt * 16 + q * 4;
            f32x4 o = acc[m][nt];
            if (XMODE) {
                fx4 bb = ld4(bias + c0);
                fx4 rr = ld4(resid + (size_t)r * 128 + c0);
                #pragma unroll
                for (int j = 0; j < 4; ++j) o[j] += rr[j] + deg * bb[j];
            } else if (BIAS) {
                fx4 bb = ld4(bias + c0);
                #pragma unroll
                for (int j = 0; j < 4; ++j) o[j] += bb[j];
            }
            if (RELU) {
                #pragma unroll
                for (int j = 0; j < 4; ++j) o[j] = fmaxf(o[j], 0.f);
            }
            if (OUTF) st4(outF + (size_t)r * 128 + c0, o);
            if (OUTB) *reinterpret_cast<us4v*>(&outB[(size_t)r * 128 + c0]) = pk4(o);
        }
    }
}

// ---- fused 2-layer MLP: out = relu(A@W1+b1)@W2 + b2 (K=128) ------------------
template <bool AF32, bool OUTF, bool OUTB>
__global__ __launch_bounds__(256) void mfma_mlp(
    const void* __restrict__ Av, const unsigned short* __restrict__ W1t,
    const float* __restrict__ b1, const unsigned short* __restrict__ W2t,
    const float* __restrict__ b2,
    float* __restrict__ outF, unsigned short* __restrict__ outB, int M)
{
    constexpr int KP = 136;
    __shared__ unsigned short Ws1[128 * KP];   // W1, later reused as H tile
    __shared__ unsigned short Ws2[128 * KP];
    const int tid = threadIdx.x;
    const int lane = tid & 63;
    const int wv = tid >> 6;
    const int row0 = blockIdx.x * 128 + wv * 32;

    for (int i = tid; i < 128 * 16; i += 256) {
        int r = i >> 4, c = (i & 15) * 8;
        *reinterpret_cast<us8*>(&Ws1[r * KP + c]) =
            *reinterpret_cast<const us8*>(&W1t[r * 128 + c]);
        *reinterpret_cast<us8*>(&Ws2[r * KP + c]) =
            *reinterpret_cast<const us8*>(&W2t[r * 128 + c]);
    }
    __syncthreads();

    const int ar = lane & 15;
    const int ak = (lane >> 4) * 8;
    const int q = lane >> 4;

    // phase 1: H = relu(A@W1 + b1)
    f32x4 acc[2][8];
    #pragma unroll
    for (int m = 0; m < 2; ++m)
        #pragma unroll
        for (int nt = 0; nt < 8; ++nt) acc[m][nt] = {0.f, 0.f, 0.f, 0.f};

    #pragma unroll
    for (int kk = 0; kk < 4; ++kk) {
        us8 a[2];
        #pragma unroll
        for (int m = 0; m < 2; ++m) {
            int row = row0 + m * 16 + ar;
            us8 t = 0;
            if (row < M) {
                if (AF32) {
                    const float* ap = (const float*)Av + (size_t)row * 128 + kk * 32 + ak;
                    fx4 x0 = ld4(ap), x1 = ld4(ap + 4);
                    #pragma unroll
                    for (int j = 0; j < 4; ++j) {
                        t[j] = f2bf(x0[j]);
                        t[4 + j] = f2bf(x1[j]);
                    }
                } else {
                    t = *reinterpret_cast<const us8*>(
                        (const unsigned short*)Av + (size_t)row * 128 + kk * 32 + ak);
                }
            }
            a[m] = t;
        }
        #pragma unroll
        for (int nt = 0; nt < 8; ++nt) {
            us8 b = *reinterpret_cast<const us8*>(&Ws1[(nt * 16 + ar) * KP + kk * 32 + ak]);
            acc[0][nt] = mfma16(b, a[0], acc[0][nt]);
            acc[1][nt] = mfma16(b, a[1], acc[1][nt]);
        }
    }
    __syncthreads();    // all waves done reading W1 before overwrite

    // write H (bf16) into Ws1 rows wv*32..+32 — 8B stores
    #pragma unroll
    for (int m = 0; m < 2; ++m) {
        int lrow = wv * 32 + m * 16 + (lane & 15);
        #pragma unroll
        for (int nt = 0; nt < 8; ++nt) {
            int c0 = nt * 16 + q * 4;
            fx4 bb = ld4(b1 + c0);
            f32x4 o = acc[m][nt];
            #pragma unroll
            for (int j = 0; j < 4; ++j) o[j] = fmaxf(o[j] + bb[j], 0.f);
            *reinterpret_cast<us4v*>(&Ws1[lrow * KP + c0]) = pk4(o);
        }
    }
    __syncthreads();

    // phase 2: out = H @ W2 + b2
    f32x4 acc2[2][8];
    #pragma unroll
    for (int m = 0; m < 2; ++m)
        #pragma unroll
        for (int nt = 0; nt < 8; ++nt) acc2[m][nt] = {0.f, 0.f, 0.f, 0.f};

    #pragma unroll
    for (int kk = 0; kk < 4; ++kk) {
        us8 a[2];
        #pragma unroll
        for (int m = 0; m < 2; ++m) {
            int lrow = wv * 32 + m * 16 + ar;
            a[m] = *reinterpret_cast<const us8*>(&Ws1[lrow * KP + kk * 32 + ak]);
        }
        #pragma unroll
        for (int nt = 0; nt < 8; ++nt) {
            us8 b = *reinterpret_cast<const us8*>(&Ws2[(nt * 16 + ar) * KP + kk * 32 + ak]);
            acc2[0][nt] = mfma16(b, a[0], acc2[0][nt]);
            acc2[1][nt] = mfma16(b, a[1], acc2[1][nt]);
        }
    }

    #pragma unroll
    for (int m = 0; m < 2; ++m) {
        int r = row0 + m * 16 + (lane & 15);
        if (r >= M) continue;
        #pragma unroll
        for (int nt = 0; nt < 8; ++nt) {
            int c0 = nt * 16 + q * 4;
            fx4 bb = ld4(b2 + c0);
            f32x4 o = acc2[m][nt];
            #pragma unroll
            for (int j = 0; j < 4; ++j) o[j] += bb[j];
            if (OUTF) st4(outF + (size_t)r * 128 + c0, o);
            if (OUTB) *reinterpret_cast<us4v*>(&outB[(size_t)r * 128 + c0]) = pk4(o);
        }
    }
}

// ---- dual-output GEMM: [O1|O2] = A[M][128] @ [Wa|Wb]; Wt is 256 rows x 128k --
__global__ __launch_bounds__(256) void mfma_gemm_dual(
    const float* __restrict__ A, const unsigned short* __restrict__ Wt,
    unsigned short* __restrict__ out1, unsigned short* __restrict__ out2, int M)
{
    constexpr int KP = 136;
    __shared__ unsigned short Ws[256 * KP];
    const int tid = threadIdx.x;
    const int lane = tid & 63;
    const int wv = tid >> 6;
    const int row0 = blockIdx.x * 128 + wv * 32;

    for (int i = tid; i < 256 * 16; i += 256) {
        int r = i >> 4, c = (i & 15) * 8;
        *reinterpret_cast<us8*>(&Ws[r * KP + c]) =
            *reinterpret_cast<const us8*>(&Wt[r * 128 + c]);
    }
    __syncthreads();

    const int ar = lane & 15;
    const int ak = (lane >> 4) * 8;
    const int q = lane >> 4;

    f32x4 acc[2][16];
    #pragma unroll
    for (int m = 0; m < 2; ++m)
        #pragma unroll
        for (int nt = 0; nt < 16; ++nt) acc[m][nt] = {0.f, 0.f, 0.f, 0.f};

    #pragma unroll
    for (int kk = 0; kk < 4; ++kk) {
        us8 a[2];
        #pragma unroll
        for (int m = 0; m < 2; ++m) {
            int row = row0 + m * 16 + ar;
            us8 t = 0;
            if (row < M) {
                const float* ap = A + (size_t)row * 128 + kk * 32 + ak;
                fx4 x0 = ld4(ap), x1 = ld4(ap + 4);
                #pragma unroll
                for (int j = 0; j < 4; ++j) {
                    t[j] = f2bf(x0[j]);
                    t[4 + j] = f2bf(x1[j]);
                }
            }
            a[m] = t;
        }
        #pragma unroll
        for (int nt = 0; nt < 16; ++nt) {
            us8 b = *reinterpret_cast<const us8*>(&Ws[(nt * 16 + ar) * KP + kk * 32 + ak]);
            acc[0][nt] = mfma16(b, a[0], acc[0][nt]);
            acc[1][nt] = mfma16(b, a[1], acc[1][nt]);
        }
    }

    #pragma unroll
    for (int m = 0; m < 2; ++m) {
        int r = row0 + m * 16 + (lane & 15);
        if (r >= M) continue;
        #pragma unroll
        for (int nt = 0; nt < 16; ++nt) {
            int c0 = (nt & 7) * 16 + q * 4;
            unsigned short* o = (nt < 8) ? out1 : out2;
            *reinterpret_cast<us4v*>(&o[(size_t)r * 128 + c0]) = pk4(acc[m][nt]);
        }
    }
}

// ---------------- fp32 helper GEMM for the tiny weight-fold (M=128) ----------
__global__ __launch_bounds__(256) void gemm128_kernel(
    const float* __restrict__ X, const float* __restrict__ W,
    float* __restrict__ Out, int M)
{
    __shared__ float Xs[64 * 132];
    const int tid = threadIdx.x;
    const int row0 = blockIdx.x * 64;

    for (int i = tid; i < 64 * 32; i += 256) {
        int r = i >> 5, c = (i & 31) * 4;
        fx4 v = {0.f, 0.f, 0.f, 0.f};
        int gr = row0 + r;
        if (gr < M) v = ld4(X + (size_t)gr * 128 + c);
        st4(&Xs[r * 132 + c], v);
    }
    __syncthreads();

    const int ty = tid >> 4, tx = tid & 15;
    fx4 acc[4][2];
    #pragma unroll
    for (int r = 0; r < 4; ++r) { acc[r][0] = 0.f; acc[r][1] = 0.f; }
    for (int k = 0; k < 128; k += 4) {
        fx4 xr[4];
        #pragma unroll
        for (int r = 0; r < 4; ++r) xr[r] = ld4(&Xs[(ty * 4 + r) * 132 + k]);
        #pragma unroll
        for (int kk = 0; kk < 4; ++kk) {
            fx4 wa = ld4(W + (size_t)(k + kk) * 128 + tx * 8);
            fx4 wb = ld4(W + (size_t)(k + kk) * 128 + tx * 8 + 4);
            #pragma unroll
            for (int r = 0; r < 4; ++r) {
                acc[r][0] += xr[r][kk] * wa;
                acc[r][1] += xr[r][kk] * wb;
            }
        }
    }
    #pragma unroll
    for (int r = 0; r < 4; ++r) {
        int gr = row0 + ty * 4 + r;
        if (gr < M) {
            st4(Out + (size_t)gr * 128 + tx * 8, acc[r][0]);
            st4(Out + (size_t)gr * 128 + tx * 8 + 4, acc[r][1]);
        }
    }
}

// ---------------- weight prep ------------------------------------------------
struct TJob { const float* src; unsigned short* dst; int K; };
struct TJobs { TJob j[16]; };

__global__ __launch_bounds__(256) void transpose_kernel(TJobs jobs) {
    TJob t = jobs.j[blockIdx.x];
    int total = 128 * t.K;
    for (int i = threadIdx.x; i < total; i += 256) {
        int n = i / t.K, k = i - n * t.K;
        t.dst[(size_t)n * t.K + k] = f2bf(t.src[(size_t)k * 128 + n]);
    }
}

__global__ __launch_bounds__(128) void bep_kernel(
    const float* __restrict__ ee_b2, const float* __restrict__ ml_w1,
    const float* __restrict__ ml_b1, float* __restrict__ bep)
{
    int l = blockIdx.x, n = threadIdx.x;
    const float* W1b = ml_w1 + (size_t)l * 384 * 128 + 128 * 128;
    float s = ml_b1[(size_t)l * 128 + n];
    for (int k = 0; k < 128; ++k) s += ee_b2[k] * W1b[(size_t)k * 128 + n];
    bep[(size_t)l * 128 + n] = s;
}

// ---------------- CSR build --------------------------------------------------
__global__ __launch_bounds__(256) void csr_hist_kernel(
    const int* __restrict__ el, int* __restrict__ cnt, int NE)
{
    int e = blockIdx.x * 256 + threadIdx.x;
    if (e < NE) {
        atomicAdd(&cnt[el[2 * (size_t)e + 1]], 1);
        atomicAdd(&cnt[el[2 * (size_t)e]], 1);
    }
}

__global__ __launch_bounds__(256) void scan_p1_kernel(
    const int* __restrict__ cnt, int* __restrict__ bsum, int NN)
{
    __shared__ int red[256];
    const int t = threadIdx.x;
    int i = blockIdx.x * 256 + t;
    red[t] = (i < NN) ? cnt[i] : 0;
    __syncthreads();
    for (int off = 128; off > 0; off >>= 1) {
        if (t < off) red[t] += red[t + off];
        __syncthreads();
    }
    if (t == 0) bsum[blockIdx.x] = red[0];
}

__global__ __launch_bounds__(256) void scan_p2_kernel(
    int* __restrict__ bsum, int* __restrict__ startp, int nb, int NN)
{
    __shared__ int part[256];
    const int t = threadIdx.x;
    int v = (t < nb) ? bsum[t] : 0;
    part[t] = v;
    __syncthreads();
    for (int off = 1; off < 256; off <<= 1) {
        int u = (t >= off) ? part[t - off] : 0;
        __syncthreads();
        part[t] += u;
        __syncthreads();
    }
    if (t < nb) bsum[t] = part[t] - v;
    if (t == 255) startp[NN] = part[255];
}

__global__ __launch_bounds__(256) void scan_p3_kernel(
    int* __restrict__ cnt, const int* __restrict__ bsum,
    int* __restrict__ startp, int NN)
{
    __shared__ int part[256];
    const int t = threadIdx.x;
    int i = blockIdx.x * 256 + t;
    int v = (i < NN) ? cnt[i] : 0;
    part[t] = v;
    __syncthreads();
    for (int off = 1; off < 256; off <<= 1) {
        int u = (t >= off) ? part[t - off] : 0;
        __syncthreads();
        part[t] += u;
        __syncthreads();
    }
    if (i < NN) {
        startp[i] = bsum[blockIdx.x] + part[t] - v;
        cnt[i] = 0;
    }
}

__global__ __launch_bounds__(256) void csr_fill_kernel(
    const int* __restrict__ el, const int* __restrict__ startp,
    int* __restrict__ cursor, int2* __restrict__ inc, int NE)
{
    int e = blockIdx.x * 256 + threadIdx.x;
    if (e < NE) {
        int s = el[2 * (size_t)e], d = el[2 * (size_t)e + 1];
        int p = startp[d] + atomicAdd(&cursor[d], 1);
        inc[p] = make_int2(s, e);
        int q = startp[s] + atomicAdd(&cursor[s], 1);
        inc[q] = make_int2(d, e);
    }
}

// ---------------- gather: S[n] = sum_j relu(P1[o_j] + Ep[e_j] + P3[n]) -------
__global__ __launch_bounds__(256) void gather_kernel(
    const unsigned short* __restrict__ P1bf, const unsigned short* __restrict__ P3bf,
    const unsigned short* __restrict__ Ep, const int2* __restrict__ inc,
    const int* __restrict__ startp, unsigned short* __restrict__ S, int M)
{
    const int tid = threadIdx.x;
    const int lane = tid & 63;
    const int n = blockIdx.x * 4 + (tid >> 6);
    if (n >= M) return;
    const int slot = lane >> 4;
    const int c = (lane & 15) * 8;

    float p3[8], acc[8];
    us8 u3 = *reinterpret_cast<const us8*>(&P3bf[(size_t)n * 128 + c]);
    #pragma unroll
    for (int i = 0; i < 8; ++i) {
        p3[i] = bf2f((unsigned int)(unsigned short)u3[i]);
        acc[i] = 0.f;
    }

    const int j1 = startp[n + 1];
    int j = startp[n] + slot;
    int2 oe = (j < j1) ? inc[j] : make_int2(0, 0);
    while (j < j1) {
        int jn = j + 4;
        int2 oen = (jn < j1) ? inc[jn] : make_int2(0, 0);
        us8 u1 = *reinterpret_cast<const us8*>(&P1bf[(size_t)oe.x * 128 + c]);
        us8 ue = *reinterpret_cast<const us8*>(&Ep[(size_t)oe.y * 128 + c]);
        #pragma unroll
        for (int i = 0; i < 8; ++i)
            acc[i] += fmaxf(p3[i] + bf2f((unsigned int)(unsigned short)u1[i])
                                  + bf2f((unsigned int)(unsigned short)ue[i]), 0.f);
        j = jn; oe = oen;
    }

    #pragma unroll
    for (int i = 0; i < 8; ++i) {
        acc[i] += __shfl_xor(acc[i], 16, 64);
        acc[i] += __shfl_xor(acc[i], 32, 64);
    }
    if (slot == 0) {
        us8 pk;
        #pragma unroll
        for (int i = 0; i < 8; ++i) pk[i] = f2bf(acc[i]);
        *reinterpret_cast<us8*>(&S[(size_t)n * 128 + c]) = pk;
    }
}

// ---------------- host launch ------------------------------------------------
extern "C" void kernel_launch(void* const* d_in, const int* in_sizes, int n_in,
                              void* d_out, int out_size, void* d_ws, size_t ws_size,
                              hipStream_t stream) {
    const float* node_f    = (const float*)d_in[0];
    const int*   edge_list = (const int*)d_in[1];
    const float* edge_f    = (const float*)d_in[2];
    const float* ne_w1 = (const float*)d_in[4];
    const float* ne_b1 = (const float*)d_in[5];
    const float* ne_w2 = (const float*)d_in[6];
    const float* ne_b2 = (const float*)d_in[7];
    const float* ee_w1 = (const float*)d_in[8];
    const float* ee_b1 = (const float*)d_in[9];
    const float* ee_w2 = (const float*)d_in[10];
    const float* ee_b2 = (const float*)d_in[11];
    const float* ml_w1 = (const float*)d_in[12];
    const float* ml_b1 = (const float*)d_in[13];
    const float* ml_w2 = (const float*)d_in[14];
    const float* ml_b2 = (const float*)d_in[15];
    const float* agg_w1 = (const float*)d_in[16];
    const float* agg_b1 = (const float*)d_in[17];
    const float* agg_w2 = (const float*)d_in[18];
    const float* agg_b2 = (const float*)d_in[19];

    const int NN = in_sizes[0] / 128;
    const int NE = in_sizes[1] / 2;
    const int n_layers = in_sizes[12] / (384 * 128);

    char* p = (char*)d_ws;
    auto alloc = [&](size_t bytes) -> void* {
        void* r = (void*)p;
        p += (bytes + 255) & ~(size_t)255;
        return r;
    };
    float* node_emb = (float*)alloc((size_t)NN * 128 * 4);
    unsigned short* P1bf = (unsigned short*)alloc((size_t)NN * 128 * 2);
    unsigned short* P3bf = (unsigned short*)alloc((size_t)NN * 128 * 2);
    unsigned short* bufS = (unsigned short*)alloc((size_t)NN * 128 * 2);
    unsigned short* H_edge = (unsigned short*)alloc((size_t)NE * 128 * 2);
    unsigned short* Ep = (unsigned short*)alloc((size_t)NE * 128 * 2);
    unsigned short* ne_w1t = (unsigned short*)alloc(128 * 128 * 2);
    unsigned short* ne_w2t = (unsigned short*)alloc(128 * 128 * 2);
    unsigned short* ee_w1t = (unsigned short*)alloc(128 * 64 * 2);
    unsigned short* aw1t = (unsigned short*)alloc(128 * 128 * 2);
    unsigned short* aw2t = (unsigned short*)alloc(128 * 128 * 2);
    unsigned short* W13t[2], *W2t[2], *Wept[2];
    float* Wepf[2];
    for (int l = 0; l < 2; ++l) {
        W13t[l] = (unsigned short*)alloc(256 * 128 * 2);
        W2t[l]  = (unsigned short*)alloc(128 * 128 * 2);
        Wept[l] = (unsigned short*)alloc(128 * 128 * 2);
        Wepf[l] = (float*)alloc(128 * 128 * 4);
    }
    float* bep = (float*)alloc((size_t)2 * 128 * 4);
    int* cnt = (int*)alloc((size_t)NN * 4);
    int* startp = (int*)alloc((size_t)(NN + 1) * 4);
    int* bsum = (int*)alloc(256 * 4);
    int2* inc = (int2*)alloc((size_t)2 * NE * 8);
    size_t need = (size_t)(p - (char*)d_ws);
    if (ws_size < need) return;

    dim3 blk(256);
    const int gM_N = (NN + 127) / 128;
    const int gM_E = (NE + 127) / 128;
    const int gE256 = (NE + 255) / 256;
    const int nbScan = (NN + 255) / 256;

    // ---- weight prep ----
    for (int l = 0; l < n_layers && l < 2; ++l) {
        const float* W1b = ml_w1 + (size_t)l * 384 * 128 + 128 * 128;
        gemm128_kernel<<<2, blk, 0, stream>>>(ee_w2, W1b, Wepf[l], 128);
    }
    {
        TJobs jobs{};
        int nj = 0;
        jobs.j[nj++] = {ne_w1, ne_w1t, 128};
        jobs.j[nj++] = {ne_w2, ne_w2t, 128};
        jobs.j[nj++] = {ee_w1, ee_w1t, 64};
        jobs.j[nj++] = {agg_w1, aw1t, 128};
        jobs.j[nj++] = {agg_w2, aw2t, 128};
        for (int l = 0; l < n_layers && l < 2; ++l) {
            jobs.j[nj++] = {ml_w1 + (size_t)l * 384 * 128, W13t[l], 128};
            jobs.j[nj++] = {ml_w1 + (size_t)l * 384 * 128 + 256 * 128, W13t[l] + 128 * 128, 128};
            jobs.j[nj++] = {ml_w2 + (size_t)l * 128 * 128, W2t[l], 128};
            jobs.j[nj++] = {Wepf[l], Wept[l], 128};
        }
        transpose_kernel<<<nj, blk, 0, stream>>>(jobs);
    }
    bep_kernel<<<n_layers, 128, 0, stream>>>(ee_b2, ml_w1, ml_b1, bep);

    // ---- encoders ----
    mfma_mlp<true, true, false><<<gM_N, blk, 0, stream>>>(
        node_f, ne_w1t, ne_b1, ne_w2t, ne_b2, node_emb, nullptr, NN);
    mfma_gemm<64, true, true, true, false, true, false><<<gM_E, blk, 0, stream>>>(
        edge_f, ee_w1t, ee_b1, nullptr, H_edge, nullptr, nullptr, NE);

    // ---- CSR incidence ----
    hipMemsetAsync(cnt, 0, (size_t)NN * sizeof(int), stream);
    csr_hist_kernel<<<gE256, blk, 0, stream>>>(edge_list, cnt, NE);
    scan_p1_kernel<<<nbScan, blk, 0, stream>>>(cnt, bsum, NN);
    scan_p2_kernel<<<1, blk, 0, stream>>>(bsum, startp, nbScan, NN);
    scan_p3_kernel<<<nbScan, blk, 0, stream>>>(cnt, bsum, startp, NN);
    csr_fill_kernel<<<gE256, blk, 0, stream>>>(edge_list, startp, cnt, inc, NE);

    float* out = (float*)d_out;
    for (int l = 0; l < n_layers && l < 2; ++l) {
        // [P1|P3] = node_emb @ [W1a|W1c]
        mfma_gemm_dual<<<gM_N, blk, 0, stream>>>(node_emb, W13t[l], P1bf, P3bf, NN);
        // Ep = H_edge @ Wep + bep
        mfma_gemm<128, false, true, false, false, true, false><<<gM_E, blk, 0, stream>>>(
            H_edge, Wept[l], bep + (size_t)l * 128, nullptr, Ep, nullptr, nullptr, NE);
        // S = gather-sum of relu'd hiddens -> bufS
        gather_kernel<<<(NN + 3) / 4, blk, 0, stream>>>(
            P1bf, P3bf, Ep, inc, startp, bufS, NN);
        // X = node_emb + S@W2 + deg*b2 -> P1bf (bf16)
        mfma_gemm<128, false, true, false, false, true, true><<<gM_N, blk, 0, stream>>>(
            bufS, W2t[l], ml_b2 + (size_t)l * 128, nullptr, P1bf, node_emb, startp, NN);
        // out = mlp(X; aw1,ab1,aw2,ab2)
        float* dst = (l == n_layers - 1) ? out : node_emb;
        mfma_mlp<false, true, false><<<gM_N, blk, 0, stream>>>(
            P1bf, aw1t, agg_b1, aw2t, agg_b2, dst, nullptr, NN);
    }
}